// Round 1
// baseline (4514.938 us; speedup 1.0000x reference)
//
#include <hip/hip_runtime.h>

// PointNetLayer: per-edge MLP (19->64->128->64, ReLU) + segment_max + node MLP (64->64, ReLU)
// Round 1: fp32 fused baseline. One thread per edge; w2/w3 in LDS (64KB);
// h3 >= 0 after ReLU => segment_max == atomicMax on int bits with 0-init.

#define RELU(v) fmaxf((v), 0.0f)

__global__ __launch_bounds__(256, 2)
void edge_mlp_kernel(const float* __restrict__ x,
                     const float* __restrict__ pos,
                     const float* __restrict__ w1, const float* __restrict__ b1,
                     const float* __restrict__ w2, const float* __restrict__ b2,
                     const float* __restrict__ w3, const float* __restrict__ b3,
                     const int* __restrict__ ei,
                     int E, int* __restrict__ agg)  // agg: [N][64] float bits, pre-zeroed
{
    __shared__ float w2s[64 * 128];   // 32 KB
    __shared__ float w3s[128 * 64];   // 32 KB

    for (int i = threadIdx.x; i < 64 * 128; i += blockDim.x) w2s[i] = w2[i];
    for (int i = threadIdx.x; i < 128 * 64; i += blockDim.x) w3s[i] = w3[i];
    __syncthreads();

    const int e = blockIdx.x * blockDim.x + threadIdx.x;
    if (e >= E) return;

    const int s = ei[e];
    const int d = ei[E + e];

    // msg = [x[s] (16), pos[s]-pos[d] (3)]
    float msg[19];
    {
        const float4* xv = reinterpret_cast<const float4*>(x + (size_t)s * 16);
        float4 x0 = xv[0], x1 = xv[1], x2 = xv[2], x3 = xv[3];
        msg[0] = x0.x;  msg[1] = x0.y;  msg[2] = x0.z;  msg[3] = x0.w;
        msg[4] = x1.x;  msg[5] = x1.y;  msg[6] = x1.z;  msg[7] = x1.w;
        msg[8] = x2.x;  msg[9] = x2.y;  msg[10] = x2.z; msg[11] = x2.w;
        msg[12] = x3.x; msg[13] = x3.y; msg[14] = x3.z; msg[15] = x3.w;
        msg[16] = pos[(size_t)s * 3 + 0] - pos[(size_t)d * 3 + 0];
        msg[17] = pos[(size_t)s * 3 + 1] - pos[(size_t)d * 3 + 1];
        msg[18] = pos[(size_t)s * 3 + 2] - pos[(size_t)d * 3 + 2];
    }

    // h1 = relu(msg @ w1 + b1)  [64] — w1/b1 via uniform (scalar) global loads
    float h1[64];
    {
        const float4* w1v = reinterpret_cast<const float4*>(w1);
        const float4* b1v = reinterpret_cast<const float4*>(b1);
        #pragma unroll
        for (int og = 0; og < 16; ++og) {
            float4 acc = b1v[og];
            #pragma unroll
            for (int k = 0; k < 19; ++k) {
                float4 w = w1v[k * 16 + og];
                float m = msg[k];
                acc.x += m * w.x; acc.y += m * w.y; acc.z += m * w.z; acc.w += m * w.w;
            }
            h1[og * 4 + 0] = RELU(acc.x);
            h1[og * 4 + 1] = RELU(acc.y);
            h1[og * 4 + 2] = RELU(acc.z);
            h1[og * 4 + 3] = RELU(acc.w);
        }
    }

    // h3 accumulators init to b3; stream h2 in groups of 4
    float4 h3[16];
    {
        const float4* b3v = reinterpret_cast<const float4*>(b3);
        #pragma unroll
        for (int og = 0; og < 16; ++og) h3[og] = b3v[og];
    }

    const float4* b2v  = reinterpret_cast<const float4*>(b2);
    const float4* w2sv = reinterpret_cast<const float4*>(w2s);
    const float4* w3sv = reinterpret_cast<const float4*>(w3s);

    #pragma unroll 1
    for (int jg = 0; jg < 32; ++jg) {
        // t = relu(h1 @ w2[:, 4jg:4jg+4] + b2[4jg:4jg+4])
        float4 t = b2v[jg];
        #pragma unroll
        for (int k = 0; k < 64; ++k) {
            float4 w = w2sv[k * 32 + jg];
            float h = h1[k];
            t.x += h * w.x; t.y += h * w.y; t.z += h * w.z; t.w += h * w.w;
        }
        t.x = RELU(t.x); t.y = RELU(t.y); t.z = RELU(t.z); t.w = RELU(t.w);

        // h3 += t @ w3[4jg:4jg+4, :]
        #pragma unroll
        for (int og = 0; og < 16; ++og) {
            float4 wa = w3sv[(jg * 4 + 0) * 16 + og];
            float4 wb = w3sv[(jg * 4 + 1) * 16 + og];
            float4 wc = w3sv[(jg * 4 + 2) * 16 + og];
            float4 wd = w3sv[(jg * 4 + 3) * 16 + og];
            h3[og].x += t.x * wa.x + t.y * wb.x + t.z * wc.x + t.w * wd.x;
            h3[og].y += t.x * wa.y + t.y * wb.y + t.z * wc.y + t.w * wd.y;
            h3[og].z += t.x * wa.z + t.y * wb.z + t.z * wc.z + t.w * wd.z;
            h3[og].w += t.x * wa.w + t.y * wb.w + t.z * wc.w + t.w * wd.w;
        }
    }

    // relu(h3) then atomic max into agg[d] (non-negative floats: int order == float order)
    int* aggp = agg + (size_t)d * 64;
    #pragma unroll
    for (int og = 0; og < 16; ++og) {
        float4 v = h3[og];
        atomicMax(&aggp[og * 4 + 0], __float_as_int(RELU(v.x)));
        atomicMax(&aggp[og * 4 + 1], __float_as_int(RELU(v.y)));
        atomicMax(&aggp[og * 4 + 2], __float_as_int(RELU(v.z)));
        atomicMax(&aggp[og * 4 + 3], __float_as_int(RELU(v.w)));
    }
}

// out = relu(agg @ wg + bg)   [N][64]
__global__ __launch_bounds__(256, 4)
void node_out_kernel(const float* __restrict__ agg, const float* __restrict__ wg,
                     const float* __restrict__ bg, float* __restrict__ out, int N)
{
    __shared__ float wgs[64 * 64];  // 16 KB
    for (int i = threadIdx.x; i < 64 * 64; i += blockDim.x) wgs[i] = wg[i];
    __syncthreads();

    const int t = blockIdx.x * blockDim.x + threadIdx.x;
    const int n = t >> 4;
    const int og = t & 15;
    if (n >= N) return;

    const float4* aggv = reinterpret_cast<const float4*>(agg + (size_t)n * 64);
    const float4* wgsv = reinterpret_cast<const float4*>(wgs);

    float4 acc = reinterpret_cast<const float4*>(bg)[og];
    #pragma unroll
    for (int kg = 0; kg < 16; ++kg) {
        float4 a = aggv[kg];
        float4 w0 = wgsv[(kg * 4 + 0) * 16 + og];
        float4 w1 = wgsv[(kg * 4 + 1) * 16 + og];
        float4 w2 = wgsv[(kg * 4 + 2) * 16 + og];
        float4 w3 = wgsv[(kg * 4 + 3) * 16 + og];
        acc.x += a.x * w0.x + a.y * w1.x + a.z * w2.x + a.w * w3.x;
        acc.y += a.x * w0.y + a.y * w1.y + a.z * w2.y + a.w * w3.y;
        acc.z += a.x * w0.z + a.y * w1.z + a.z * w2.z + a.w * w3.z;
        acc.w += a.x * w0.w + a.y * w1.w + a.z * w2.w + a.w * w3.w;
    }
    float4 r;
    r.x = RELU(acc.x); r.y = RELU(acc.y); r.z = RELU(acc.z); r.w = RELU(acc.w);
    reinterpret_cast<float4*>(out)[(size_t)n * 16 + og] = r;
}

extern "C" void kernel_launch(void* const* d_in, const int* in_sizes, int n_in,
                              void* d_out, int out_size, void* d_ws, size_t ws_size,
                              hipStream_t stream)
{
    const float* x   = (const float*)d_in[0];
    const float* pos = (const float*)d_in[1];
    const float* w1  = (const float*)d_in[2];
    const float* b1  = (const float*)d_in[3];
    const float* w2  = (const float*)d_in[4];
    const float* b2  = (const float*)d_in[5];
    const float* w3  = (const float*)d_in[6];
    const float* b3  = (const float*)d_in[7];
    const float* wg  = (const float*)d_in[8];
    const float* bg  = (const float*)d_in[9];
    const int*   ei  = (const int*)d_in[10];

    const int N = in_sizes[0] / 16;
    const int E = in_sizes[10] / 2;

    int* agg = (int*)d_ws;  // [N][64] float bits
    hipMemsetAsync(agg, 0, (size_t)N * 64 * sizeof(int), stream);

    edge_mlp_kernel<<<(E + 255) / 256, 256, 0, stream>>>(
        x, pos, w1, b1, w2, b2, w3, b3, ei, E, agg);

    node_out_kernel<<<(N * 16 + 255) / 256, 256, 0, stream>>>(
        (const float*)agg, wg, bg, (float*)d_out, N);
}

// Round 2
// 2092.338 us; speedup vs baseline: 2.1578x; 2.1578x over previous
//
#include <hip/hip_runtime.h>

// PointNetLayer: per-edge MLP (19->64->128->64, ReLU) + segment_max + node MLP (64->64, ReLU)
// Round 2: counting-sort edges by dst, wave-segmented shuffle max, head-only atomics.
// Round-1 showed the 102M global atomicMax = 3.2GB HBM RMW was the bottleneck (731 GB/s * 4.58ms).

#define RELU(v) fmaxf((v), 0.0f)

// ---------- pass 1: histogram ----------
__global__ void count_kernel(const int* __restrict__ ei, int E, int* __restrict__ cnt)
{
    int e = blockIdx.x * blockDim.x + threadIdx.x;
    if (e < E) atomicAdd(&cnt[ei[E + e]], 1);
}

// ---------- pass 2: exclusive scan (single 1024-thread block) ----------
__global__ __launch_bounds__(1024)
void scan_kernel(const int* __restrict__ cnt, int* __restrict__ cur, int N)
{
    __shared__ int part[1024];
    __shared__ int partscan[1024];
    const int t = threadIdx.x;
    const int C = (N + 1023) / 1024;
    const int lo = t * C;
    const int hi = min(lo + C, N);

    int s = 0;
    for (int i = lo; i < hi; ++i) s += cnt[i];
    part[t] = s;
    __syncthreads();
    if (t == 0) {
        int run = 0;
        for (int i = 0; i < 1024; ++i) { partscan[i] = run; run += part[i]; }
    }
    __syncthreads();
    int run = partscan[t];
    for (int i = lo; i < hi; ++i) { cur[i] = run; run += cnt[i]; }
}

// ---------- pass 3: scatter edge ids into dst-sorted order ----------
__global__ void scatter_kernel(const int* __restrict__ ei, int E, int* __restrict__ cur,
                               int* __restrict__ esrc, int* __restrict__ edst)
{
    int e = blockIdx.x * blockDim.x + threadIdx.x;
    if (e >= E) return;
    int s = ei[e];
    int d = ei[E + e];
    int p = atomicAdd(&cur[d], 1);
    esrc[p] = s;
    edst[p] = d;
}

// ---------- pass 4: edge MLP + wave-segmented max + head atomics ----------
__global__ __launch_bounds__(256, 2)
void edge_mlp_kernel(const float* __restrict__ x,
                     const float* __restrict__ pos,
                     const float* __restrict__ w1, const float* __restrict__ b1,
                     const float* __restrict__ w2, const float* __restrict__ b2,
                     const float* __restrict__ w3, const float* __restrict__ b3,
                     const int* __restrict__ esrc, const int* __restrict__ edst,
                     int E, int* __restrict__ agg)  // agg: [N][64] float bits, pre-zeroed
{
    __shared__ float w2s[64 * 128];   // 32 KB
    __shared__ float w3s[128 * 64];   // 32 KB

    for (int i = threadIdx.x; i < 64 * 128; i += blockDim.x) w2s[i] = w2[i];
    for (int i = threadIdx.x; i < 128 * 64; i += blockDim.x) w3s[i] = w3[i];
    __syncthreads();

    const int p = blockIdx.x * blockDim.x + threadIdx.x;
    if (p >= E) return;

    const int s = esrc[p];
    const int d = edst[p];

    // msg = [x[s] (16), pos[s]-pos[d] (3)]
    float msg[19];
    {
        const float4* xv = reinterpret_cast<const float4*>(x + (size_t)s * 16);
        float4 x0 = xv[0], x1 = xv[1], x2 = xv[2], x3 = xv[3];
        msg[0] = x0.x;  msg[1] = x0.y;  msg[2] = x0.z;  msg[3] = x0.w;
        msg[4] = x1.x;  msg[5] = x1.y;  msg[6] = x1.z;  msg[7] = x1.w;
        msg[8] = x2.x;  msg[9] = x2.y;  msg[10] = x2.z; msg[11] = x2.w;
        msg[12] = x3.x; msg[13] = x3.y; msg[14] = x3.z; msg[15] = x3.w;
        msg[16] = pos[(size_t)s * 3 + 0] - pos[(size_t)d * 3 + 0];
        msg[17] = pos[(size_t)s * 3 + 1] - pos[(size_t)d * 3 + 1];
        msg[18] = pos[(size_t)s * 3 + 2] - pos[(size_t)d * 3 + 2];
    }

    // h1 = relu(msg @ w1 + b1)
    float h1[64];
    {
        const float4* w1v = reinterpret_cast<const float4*>(w1);
        const float4* b1v = reinterpret_cast<const float4*>(b1);
        #pragma unroll
        for (int og = 0; og < 16; ++og) {
            float4 acc = b1v[og];
            #pragma unroll
            for (int k = 0; k < 19; ++k) {
                float4 w = w1v[k * 16 + og];
                float m = msg[k];
                acc.x += m * w.x; acc.y += m * w.y; acc.z += m * w.z; acc.w += m * w.w;
            }
            h1[og * 4 + 0] = RELU(acc.x);
            h1[og * 4 + 1] = RELU(acc.y);
            h1[og * 4 + 2] = RELU(acc.z);
            h1[og * 4 + 3] = RELU(acc.w);
        }
    }

    // h3 accumulators init to b3; stream h2 in groups of 4
    float4 h3[16];
    {
        const float4* b3v = reinterpret_cast<const float4*>(b3);
        #pragma unroll
        for (int og = 0; og < 16; ++og) h3[og] = b3v[og];
    }

    const float4* b2v  = reinterpret_cast<const float4*>(b2);
    const float4* w2sv = reinterpret_cast<const float4*>(w2s);
    const float4* w3sv = reinterpret_cast<const float4*>(w3s);

    #pragma unroll 1
    for (int jg = 0; jg < 32; ++jg) {
        float4 t = b2v[jg];
        #pragma unroll
        for (int k = 0; k < 64; ++k) {
            float4 w = w2sv[k * 32 + jg];
            float h = h1[k];
            t.x += h * w.x; t.y += h * w.y; t.z += h * w.z; t.w += h * w.w;
        }
        t.x = RELU(t.x); t.y = RELU(t.y); t.z = RELU(t.z); t.w = RELU(t.w);

        #pragma unroll
        for (int og = 0; og < 16; ++og) {
            float4 wa = w3sv[(jg * 4 + 0) * 16 + og];
            float4 wb = w3sv[(jg * 4 + 1) * 16 + og];
            float4 wc = w3sv[(jg * 4 + 2) * 16 + og];
            float4 wd = w3sv[(jg * 4 + 3) * 16 + og];
            h3[og].x += t.x * wa.x + t.y * wb.x + t.z * wc.x + t.w * wd.x;
            h3[og].y += t.x * wa.y + t.y * wb.y + t.z * wc.y + t.w * wd.y;
            h3[og].z += t.x * wa.z + t.y * wb.z + t.z * wc.z + t.w * wd.z;
            h3[og].w += t.x * wa.w + t.y * wb.w + t.z * wc.w + t.w * wd.w;
        }
    }

    // ReLU h3 (needed for int-bits max trick and before reduction)
    #pragma unroll
    for (int og = 0; og < 16; ++og) {
        h3[og].x = RELU(h3[og].x); h3[og].y = RELU(h3[og].y);
        h3[og].z = RELU(h3[og].z); h3[og].w = RELU(h3[og].w);
    }

    // wave-segmented jump-max over sorted dst runs (max is idempotent; sorted =>
    // equal-dst lanes contiguous, so (d[lane+s]==d[lane]) implies whole range equal)
    const int lane = threadIdx.x & 63;
    #pragma unroll
    for (int sft = 1; sft < 64; sft <<= 1) {
        int dn = __shfl_down(d, sft);
        bool take = (lane + sft < 64) && (dn == d);
        #pragma unroll
        for (int og = 0; og < 16; ++og) {
            float vx = __shfl_down(h3[og].x, sft);
            float vy = __shfl_down(h3[og].y, sft);
            float vz = __shfl_down(h3[og].z, sft);
            float vw = __shfl_down(h3[og].w, sft);
            if (take) {
                h3[og].x = fmaxf(h3[og].x, vx);
                h3[og].y = fmaxf(h3[og].y, vy);
                h3[og].z = fmaxf(h3[og].z, vz);
                h3[og].w = fmaxf(h3[og].w, vw);
            }
        }
    }

    int dprev = __shfl_up(d, 1);
    bool head = (lane == 0) || (dprev != d);
    if (head) {
        int* aggp = agg + (size_t)d * 64;
        #pragma unroll
        for (int og = 0; og < 16; ++og) {
            atomicMax(&aggp[og * 4 + 0], __float_as_int(h3[og].x));
            atomicMax(&aggp[og * 4 + 1], __float_as_int(h3[og].y));
            atomicMax(&aggp[og * 4 + 2], __float_as_int(h3[og].z));
            atomicMax(&aggp[og * 4 + 3], __float_as_int(h3[og].w));
        }
    }
}

// ---------- pass 5: out = relu(agg @ wg + bg) ----------
__global__ __launch_bounds__(256, 4)
void node_out_kernel(const float* __restrict__ agg, const float* __restrict__ wg,
                     const float* __restrict__ bg, float* __restrict__ out, int N)
{
    __shared__ float wgs[64 * 64];  // 16 KB
    for (int i = threadIdx.x; i < 64 * 64; i += blockDim.x) wgs[i] = wg[i];
    __syncthreads();

    const int t = blockIdx.x * blockDim.x + threadIdx.x;
    const int n = t >> 4;
    const int og = t & 15;
    if (n >= N) return;

    const float4* aggv = reinterpret_cast<const float4*>(agg + (size_t)n * 64);
    const float4* wgsv = reinterpret_cast<const float4*>(wgs);

    float4 acc = reinterpret_cast<const float4*>(bg)[og];
    #pragma unroll
    for (int kg = 0; kg < 16; ++kg) {
        float4 a = aggv[kg];
        float4 w0 = wgsv[(kg * 4 + 0) * 16 + og];
        float4 w1 = wgsv[(kg * 4 + 1) * 16 + og];
        float4 w2 = wgsv[(kg * 4 + 2) * 16 + og];
        float4 w3 = wgsv[(kg * 4 + 3) * 16 + og];
        acc.x += a.x * w0.x + a.y * w1.x + a.z * w2.x + a.w * w3.x;
        acc.y += a.x * w0.y + a.y * w1.y + a.z * w2.y + a.w * w3.y;
        acc.z += a.x * w0.z + a.y * w1.z + a.z * w2.z + a.w * w3.z;
        acc.w += a.x * w0.w + a.y * w1.w + a.z * w2.w + a.w * w3.w;
    }
    float4 r;
    r.x = RELU(acc.x); r.y = RELU(acc.y); r.z = RELU(acc.z); r.w = RELU(acc.w);
    reinterpret_cast<float4*>(out)[(size_t)n * 16 + og] = r;
}

extern "C" void kernel_launch(void* const* d_in, const int* in_sizes, int n_in,
                              void* d_out, int out_size, void* d_ws, size_t ws_size,
                              hipStream_t stream)
{
    const float* x   = (const float*)d_in[0];
    const float* pos = (const float*)d_in[1];
    const float* w1  = (const float*)d_in[2];
    const float* b1  = (const float*)d_in[3];
    const float* w2  = (const float*)d_in[4];
    const float* b2  = (const float*)d_in[5];
    const float* w3  = (const float*)d_in[6];
    const float* b3  = (const float*)d_in[7];
    const float* wg  = (const float*)d_in[8];
    const float* bg  = (const float*)d_in[9];
    const int*   ei  = (const int*)d_in[10];

    const int N = in_sizes[0] / 16;
    const int E = in_sizes[10] / 2;

    // ws layout (int elements)
    int* wsi  = (int*)d_ws;
    int* cnt  = wsi;                     // [N]
    int* cur  = wsi + 102400;            // [N]
    int* esrc = wsi + 204800;            // [E]
    int* edst = wsi + 204800 + E;        // [E]
    int* agg  = wsi + 204800 + 2 * E;    // [N*64] float bits

    hipMemsetAsync(cnt, 0, (size_t)N * sizeof(int), stream);
    hipMemsetAsync(agg, 0, (size_t)N * 64 * sizeof(int), stream);

    const int eb = (E + 255) / 256;
    count_kernel<<<eb, 256, 0, stream>>>(ei, E, cnt);
    scan_kernel<<<1, 1024, 0, stream>>>(cnt, cur, N);
    scatter_kernel<<<eb, 256, 0, stream>>>(ei, E, cur, esrc, edst);
    edge_mlp_kernel<<<eb, 256, 0, stream>>>(
        x, pos, w1, b1, w2, b2, w3, b3, esrc, edst, E, agg);
    node_out_kernel<<<(N * 16 + 255) / 256, 256, 0, stream>>>(
        (const float*)agg, wg, bg, (float*)d_out, N);
}

// Round 3
// 1766.336 us; speedup vs baseline: 2.5561x; 1.1846x over previous
//
#include <hip/hip_runtime.h>

// PointNetLayer round 3: fp16 MFMA for layers 2/3, layer-1 computed in A-frag layout,
// pre-swizzled weight images in LDS, sorted-run reduction with block-interior plain
// stores + boundary-only atomics.

typedef __attribute__((ext_vector_type(8))) _Float16 half8;
typedef __attribute__((ext_vector_type(4))) float floatx4;

#define RELU(v) fmaxf((v), 0.0f)

// ---------- sort pass 1: histogram ----------
__global__ void count_kernel(const int* __restrict__ ei, int E, int* __restrict__ cnt)
{
    int e = blockIdx.x * blockDim.x + threadIdx.x;
    if (e < E) atomicAdd(&cnt[ei[E + e]], 1);
}

// ---------- sort pass 2: exclusive scan (single block, Hillis-Steele) ----------
__global__ __launch_bounds__(1024)
void scan_kernel(const int* __restrict__ cnt, int* __restrict__ cur, int N)
{
    __shared__ int part[1024];
    const int t = threadIdx.x;
    const int C = (N + 1023) / 1024;
    const int lo = t * C;
    const int hi = min(lo + C, N);

    int s = 0;
    for (int i = lo; i < hi; ++i) s += cnt[i];
    part[t] = s;
    __syncthreads();
    for (int off = 1; off < 1024; off <<= 1) {
        int o = (t >= off) ? part[t - off] : 0;
        __syncthreads();
        part[t] += o;
        __syncthreads();
    }
    int run = part[t] - s;   // exclusive prefix of this chunk
    for (int i = lo; i < hi; ++i) { cur[i] = run; run += cnt[i]; }
}

// ---------- sort pass 3: scatter ----------
__global__ void scatter_kernel(const int* __restrict__ ei, int E, int* __restrict__ cur,
                               int* __restrict__ esrc, int* __restrict__ edst)
{
    int e = blockIdx.x * blockDim.x + threadIdx.x;
    if (e >= E) return;
    int s = ei[e];
    int d = ei[E + e];
    int p = atomicAdd(&cur[d], 1);
    esrc[p] = s;
    edst[p] = d;
}

// ---------- weight image prep: fp16, LDS-image layout with XOR chunk swizzle ----------
// w2img: [o=0..127][cpr=0..7][j=0..7]   element = w2[k][o], k = (cpr^(o&7))*8 + j
// w3img: [o=0..63][cpr=0..15][j=0..7]   element = w3[k][o], k = ((cpr^(o&7)))*8 + j  (XOR low 3 bits)
__global__ void prep_weights(const float* __restrict__ w2, const float* __restrict__ w3,
                             _Float16* __restrict__ w2img, _Float16* __restrict__ w3img)
{
    int t = blockIdx.x * blockDim.x + threadIdx.x;
    int stride = gridDim.x * blockDim.x;
    for (int i = t; i < 128 * 64; i += stride) {
        int o = i >> 6, cpr = (i >> 3) & 7, j = i & 7;
        int k = ((cpr ^ (o & 7)) << 3) | j;
        w2img[i] = (_Float16)w2[k * 128 + o];
    }
    for (int i = t; i < 64 * 128; i += stride) {
        int o = i >> 7, cpr = (i >> 3) & 15, j = i & 7;
        int kc = cpr ^ (o & 7);   // flips low 3 bits only
        int k = (kc << 3) | j;
        w3img[i] = (_Float16)w3[k * 64 + o];
    }
}

// ---------- main fused edge kernel ----------
// Block: 256 threads (4 waves), 64 edges. Wave tiles:
//   L2: C[64e][128o]: wave = 32e x 64o  (ebase=(w>>1)*32, obase=(w&1)*64)
//   L3: C[64e][64o] : wave = 32e x 32o  (ebase=(w>>1)*32, obase=(w&1)*32)
// MFMA 16x16x32 f16 layout assumed: A row m=lane&15, k=(lane>>4)*8+j; B col n=lane&15 same k;
// C/D col n=lane&15, row=(lane>>4)*4+reg (m89-verified). Any k-permutation error cancels
// because A and B are both constructed with the same mapping.
__global__ __launch_bounds__(256, 2)
void edge_mlp_mfma(const float* __restrict__ x, const float* __restrict__ pos,
                   const float* __restrict__ w1, const float* __restrict__ b1,
                   const _Float16* __restrict__ w2img, const float* __restrict__ b2,
                   const _Float16* __restrict__ w3img, const float* __restrict__ b3,
                   const int* __restrict__ esrc, const int* __restrict__ edst,
                   int E, float* __restrict__ aggf)
{
    __shared__ __align__(16) _Float16 w2s[128 * 64];  // 16 KB
    __shared__ __align__(16) _Float16 w3s[64 * 128];  // 16 KB
    __shared__ __align__(16) _Float16 h2s[64 * 128];  // 16 KB  [e][cpr][j], cpr=(k2>>3)^(e&7)
    __shared__ __align__(16) float    h3s[64 * 64];   // 16 KB  [e][c ^ (((e>>2)&3)<<4)]
    __shared__ int srcs[64], dsts[64];

    const int t  = threadIdx.x;
    const int bs = blockIdx.x * 64;
    const int n  = min(64, E - bs);

    // stage weight images (pre-swizzled -> linear copy, conflict-free)
    {
        const int4* s2 = (const int4*)w2img;
        int4* d2 = (int4*)w2s;
        for (int i = t; i < 1024; i += 256) d2[i] = s2[i];
        const int4* s3 = (const int4*)w3img;
        int4* d3 = (int4*)w3s;
        for (int i = t; i < 1024; i += 256) d3[i] = s3[i];
    }
    if (t < 64) {
        int idx = min(bs + t, E - 1);
        srcs[t] = esrc[idx];
        dsts[t] = edst[idx];
    }
    __syncthreads();

    const int lane = t & 63;
    const int w    = t >> 6;
    const int g    = lane >> 4;
    const int li   = lane & 15;
    const int ebL2 = (w >> 1) * 32;
    const int obL2 = (w & 1) * 64;

    // ---- layer 1 (fp32) directly into L2 A-fragments ----
    half8 afr[2][2];   // [mf][ks]
    #pragma unroll
    for (int mf = 0; mf < 2; ++mf) {
        const int eloc = ebL2 + mf * 16 + li;
        const int s = srcs[eloc];
        const int d = dsts[eloc];
        float msg[19];
        {
            const float4* xv = reinterpret_cast<const float4*>(x + (size_t)s * 16);
            float4 x0 = xv[0], x1 = xv[1], x2 = xv[2], x3 = xv[3];
            msg[0] = x0.x;  msg[1] = x0.y;  msg[2] = x0.z;  msg[3] = x0.w;
            msg[4] = x1.x;  msg[5] = x1.y;  msg[6] = x1.z;  msg[7] = x1.w;
            msg[8] = x2.x;  msg[9] = x2.y;  msg[10] = x2.z; msg[11] = x2.w;
            msg[12] = x3.x; msg[13] = x3.y; msg[14] = x3.z; msg[15] = x3.w;
            msg[16] = pos[(size_t)s * 3 + 0] - pos[(size_t)d * 3 + 0];
            msg[17] = pos[(size_t)s * 3 + 1] - pos[(size_t)d * 3 + 1];
            msg[18] = pos[(size_t)s * 3 + 2] - pos[(size_t)d * 3 + 2];
        }
        #pragma unroll
        for (int ks = 0; ks < 2; ++ks) {
            const int ch0 = ks * 32 + g * 8;
            const float4* bv = reinterpret_cast<const float4*>(b1 + ch0);
            float4 ba = bv[0], bb = bv[1];
            float acc[8] = {ba.x, ba.y, ba.z, ba.w, bb.x, bb.y, bb.z, bb.w};
            #pragma unroll
            for (int k = 0; k < 19; ++k) {
                const float4* wr = reinterpret_cast<const float4*>(w1 + k * 64 + ch0);
                float4 wa = wr[0], wb = wr[1];
                float m = msg[k];
                acc[0] += m * wa.x; acc[1] += m * wa.y; acc[2] += m * wa.z; acc[3] += m * wa.w;
                acc[4] += m * wb.x; acc[5] += m * wb.y; acc[6] += m * wb.z; acc[7] += m * wb.w;
            }
            half8 h;
            #pragma unroll
            for (int j = 0; j < 8; ++j) h[j] = (_Float16)RELU(acc[j]);
            afr[mf][ks] = h;
        }
    }

    // ---- layer 2: [64x64] x [64x128] ----
    floatx4 acc2[2][4];
    #pragma unroll
    for (int nf = 0; nf < 4; ++nf) {
        float bv = b2[obL2 + nf * 16 + li];
        #pragma unroll
        for (int mf = 0; mf < 2; ++mf) acc2[mf][nf] = (floatx4){bv, bv, bv, bv};
    }
    #pragma unroll
    for (int ks = 0; ks < 2; ++ks) {
        #pragma unroll
        for (int nf = 0; nf < 4; ++nf) {
            const int o = obL2 + nf * 16 + li;
            const int cpr = (ks * 4 + g) ^ (o & 7);
            half8 bfr = *(const half8*)&w2s[o * 64 + cpr * 8];
            #pragma unroll
            for (int mf = 0; mf < 2; ++mf)
                acc2[mf][nf] = __builtin_amdgcn_mfma_f32_16x16x32_f16(
                    afr[mf][ks], bfr, acc2[mf][nf], 0, 0, 0);
        }
    }
    // epilogue: relu -> fp16 -> h2s (swizzled)
    #pragma unroll
    for (int mf = 0; mf < 2; ++mf)
        #pragma unroll
        for (int nf = 0; nf < 4; ++nf)
            #pragma unroll
            for (int r = 0; r < 4; ++r) {
                const int e = ebL2 + mf * 16 + g * 4 + r;
                const int o = obL2 + nf * 16 + li;
                const int cpr = (o >> 3) ^ (e & 7);
                h2s[e * 128 + cpr * 8 + (o & 7)] = (_Float16)RELU(acc2[mf][nf][r]);
            }
    __syncthreads();

    // ---- layer 3: [64x128] x [128x64] ----
    const int obL3 = (w & 1) * 32;
    floatx4 acc3[2][2];
    #pragma unroll
    for (int nf = 0; nf < 2; ++nf) {
        float bv = b3[obL3 + nf * 16 + li];
        #pragma unroll
        for (int mf = 0; mf < 2; ++mf) acc3[mf][nf] = (floatx4){bv, bv, bv, bv};
    }
    #pragma unroll
    for (int ks = 0; ks < 4; ++ks) {
        half8 a2[2], b2f[2];
        #pragma unroll
        for (int mf = 0; mf < 2; ++mf) {
            const int e = ebL2 + mf * 16 + li;
            const int cpr = (ks * 4 + g) ^ (e & 7);
            a2[mf] = *(const half8*)&h2s[e * 128 + cpr * 8];
        }
        #pragma unroll
        for (int nf = 0; nf < 2; ++nf) {
            const int o = obL3 + nf * 16 + li;
            const int cpr = (ks * 4 + g) ^ (o & 7);
            b2f[nf] = *(const half8*)&w3s[o * 128 + cpr * 8];
        }
        #pragma unroll
        for (int mf = 0; mf < 2; ++mf)
            #pragma unroll
            for (int nf = 0; nf < 2; ++nf)
                acc3[mf][nf] = __builtin_amdgcn_mfma_f32_16x16x32_f16(
                    a2[mf], b2f[nf], acc3[mf][nf], 0, 0, 0);
    }
    // epilogue: relu -> h3s (bank-spread swizzle on c)
    #pragma unroll
    for (int mf = 0; mf < 2; ++mf)
        #pragma unroll
        for (int nf = 0; nf < 2; ++nf)
            #pragma unroll
            for (int r = 0; r < 4; ++r) {
                const int e = ebL2 + mf * 16 + g * 4 + r;
                const int c = obL3 + nf * 16 + li;
                h3s[e * 64 + (c ^ (((e >> 2) & 3) << 4))] = RELU(acc3[mf][nf][r]);
            }
    __syncthreads();

    // ---- sorted-run reduction: wave 0 scans the block's edges ----
    if (t < 64) {
        const int c = t;
        const int prevd = (bs == 0) ? -2 : edst[bs - 1];
        const int nextd = (bs + n >= E) ? -2 : edst[bs + n];
        int curd = -1;
        float mv = 0.0f;
        for (int i = 0; i < n; ++i) {
            const int d = dsts[i];
            const float v = h3s[i * 64 + (c ^ (((i >> 2) & 3) << 4))];
            if (d != curd) {
                if (curd >= 0) {
                    if (curd == prevd || curd == nextd)
                        atomicMax((int*)&aggf[(size_t)curd * 64 + c], __float_as_int(mv));
                    else
                        aggf[(size_t)curd * 64 + c] = mv;
                }
                curd = d;
                mv = v;
            } else {
                mv = fmaxf(mv, v);
            }
        }
        if (curd >= 0) {
            if (curd == prevd || curd == nextd)
                atomicMax((int*)&aggf[(size_t)curd * 64 + c], __float_as_int(mv));
            else
                aggf[(size_t)curd * 64 + c] = mv;
        }
    }
}

// ---------- node MLP: out = relu(agg @ wg + bg) ----------
__global__ __launch_bounds__(256, 4)
void node_out_kernel(const float* __restrict__ agg, const float* __restrict__ wg,
                     const float* __restrict__ bg, float* __restrict__ out, int N)
{
    __shared__ float wgs[64 * 64];
    for (int i = threadIdx.x; i < 64 * 64; i += blockDim.x) wgs[i] = wg[i];
    __syncthreads();

    const int t = blockIdx.x * blockDim.x + threadIdx.x;
    const int nidx = t >> 4;
    const int og = t & 15;
    if (nidx >= N) return;

    const float4* aggv = reinterpret_cast<const float4*>(agg + (size_t)nidx * 64);
    const float4* wgsv = reinterpret_cast<const float4*>(wgs);

    float4 acc = reinterpret_cast<const float4*>(bg)[og];
    #pragma unroll
    for (int kg = 0; kg < 16; ++kg) {
        float4 a = aggv[kg];
        float4 w0 = wgsv[(kg * 4 + 0) * 16 + og];
        float4 w1 = wgsv[(kg * 4 + 1) * 16 + og];
        float4 w2 = wgsv[(kg * 4 + 2) * 16 + og];
        float4 w3 = wgsv[(kg * 4 + 3) * 16 + og];
        acc.x += a.x * w0.x + a.y * w1.x + a.z * w2.x + a.w * w3.x;
        acc.y += a.x * w0.y + a.y * w1.y + a.z * w2.y + a.w * w3.y;
        acc.z += a.x * w0.z + a.y * w1.z + a.z * w2.z + a.w * w3.z;
        acc.w += a.x * w0.w + a.y * w1.w + a.z * w2.w + a.w * w3.w;
    }
    float4 r;
    r.x = RELU(acc.x); r.y = RELU(acc.y); r.z = RELU(acc.z); r.w = RELU(acc.w);
    reinterpret_cast<float4*>(out)[(size_t)nidx * 16 + og] = r;
}

extern "C" void kernel_launch(void* const* d_in, const int* in_sizes, int n_in,
                              void* d_out, int out_size, void* d_ws, size_t ws_size,
                              hipStream_t stream)
{
    const float* x   = (const float*)d_in[0];
    const float* pos = (const float*)d_in[1];
    const float* w1  = (const float*)d_in[2];
    const float* b1  = (const float*)d_in[3];
    const float* w2  = (const float*)d_in[4];
    const float* b2  = (const float*)d_in[5];
    const float* w3  = (const float*)d_in[6];
    const float* b3  = (const float*)d_in[7];
    const float* wg  = (const float*)d_in[8];
    const float* bg  = (const float*)d_in[9];
    const int*   ei  = (const int*)d_in[10];

    const int N = in_sizes[0] / 16;
    const int E = in_sizes[10] / 2;

    // ws layout (int elements)
    int* wsi  = (int*)d_ws;
    int* cnt  = wsi;                         // [N]
    int* cur  = wsi + 102400;                // [N]
    int* esrc = wsi + 204800;                // [E]
    int* edst = wsi + 204800 + E;            // [E]
    int* agg  = wsi + 204800 + 2 * E;        // [N*64] float
    _Float16* w2img = (_Float16*)(wsi + 204800 + 2 * E + 6400000);  // [8192]
    _Float16* w3img = w2img + 8192;                                  // [8192]

    hipMemsetAsync(cnt, 0, (size_t)N * sizeof(int), stream);
    hipMemsetAsync(agg, 0, (size_t)N * 64 * sizeof(int), stream);

    const int eb = (E + 255) / 256;
    prep_weights<<<8, 256, 0, stream>>>(w2, w3, w2img, w3img);
    count_kernel<<<eb, 256, 0, stream>>>(ei, E, cnt);
    scan_kernel<<<1, 1024, 0, stream>>>(cnt, cur, N);
    scatter_kernel<<<eb, 256, 0, stream>>>(ei, E, cur, esrc, edst);
    edge_mlp_mfma<<<(E + 63) / 64, 256, 0, stream>>>(
        x, pos, w1, b1, w2img, b2, w3img, b3, esrc, edst, E, (float*)agg);
    node_out_kernel<<<(N * 16 + 255) / 256, 256, 0, stream>>>(
        (const float*)agg, wg, bg, (float*)d_out, N);
}

// Round 4
// 705.783 us; speedup vs baseline: 6.3971x; 2.5027x over previous
//
#include <hip/hip_runtime.h>
#include <limits.h>

// PointNetLayer round 4: EPB=256 (4x weight-staging amortization), per-wave
// independent 64-edge MFMA pipelines (no cross-wave barriers after staging),
// w1/biases in LDS, int2 edge pairs, parallel 3-kernel scan.

typedef __attribute__((ext_vector_type(8))) _Float16 half8;
typedef __attribute__((ext_vector_type(4))) float floatx4;

#define RELU(v) fmaxf((v), 0.0f)

// ---------- sort pass 1: histogram ----------
__global__ void count_kernel(const int* __restrict__ ei, int E, int* __restrict__ cnt)
{
    int e = blockIdx.x * blockDim.x + threadIdx.x;
    if (e < E) atomicAdd(&cnt[ei[E + e]], 1);
}

// ---------- sort pass 2: parallel exclusive scan (3 kernels) ----------
__global__ __launch_bounds__(1024)
void scan1_kernel(const int* __restrict__ cnt, int* __restrict__ cur,
                  int* __restrict__ bsum, int N)
{
    __shared__ int sh[1024];
    const int t = threadIdx.x, b = blockIdx.x;
    const int idx = b * 1024 + t;
    int v = (idx < N) ? cnt[idx] : 0;
    sh[t] = v;
    __syncthreads();
    for (int off = 1; off < 1024; off <<= 1) {
        int o = (t >= off) ? sh[t - off] : 0;
        __syncthreads();
        sh[t] += o;
        __syncthreads();
    }
    if (idx < N) cur[idx] = sh[t] - v;      // exclusive within block
    if (t == 1023) bsum[b] = sh[t];
}

__global__ __launch_bounds__(128)
void scan2_kernel(int* __restrict__ bsum, int NB)
{
    __shared__ int sh[128];
    const int t = threadIdx.x;
    int v = (t < NB) ? bsum[t] : 0;
    sh[t] = v;
    __syncthreads();
    for (int off = 1; off < 128; off <<= 1) {
        int o = (t >= off) ? sh[t - off] : 0;
        __syncthreads();
        sh[t] += o;
        __syncthreads();
    }
    if (t < NB) bsum[t] = sh[t] - v;        // exclusive block offsets
}

__global__ void scan3_kernel(int* __restrict__ cur, const int* __restrict__ bsum, int N)
{
    int idx = blockIdx.x * blockDim.x + threadIdx.x;
    if (idx < N) cur[idx] += bsum[idx >> 10];
}

// ---------- sort pass 3: scatter (s,d) as int2 ----------
__global__ void scatter_kernel(const int* __restrict__ ei, int E, int* __restrict__ cur,
                               int2* __restrict__ ep)
{
    int e = blockIdx.x * blockDim.x + threadIdx.x;
    if (e >= E) return;
    int s = ei[e], d = ei[E + e];
    int p = atomicAdd(&cur[d], 1);
    ep[p] = make_int2(s, d);
}

// ---------- weight image prep: fp16 LDS-image layout with XOR chunk swizzle ----------
// w2img: [o=0..127][cpr=0..7][j=0..7]  element = w2[k][o], k = (cpr^(o&7))*8 + j
// w3img: [o=0..63][cpr=0..15][j=0..7]  element = w3[k][o], k = ((cpr^(o&7)))*8 + j
__global__ void prep_weights(const float* __restrict__ w2, const float* __restrict__ w3,
                             _Float16* __restrict__ w2img, _Float16* __restrict__ w3img)
{
    int t = blockIdx.x * blockDim.x + threadIdx.x;
    int stride = gridDim.x * blockDim.x;
    for (int i = t; i < 128 * 64; i += stride) {
        int o = i >> 6, cpr = (i >> 3) & 7, j = i & 7;
        int k = ((cpr ^ (o & 7)) << 3) | j;
        w2img[i] = (_Float16)w2[k * 128 + o];
    }
    for (int i = t; i < 64 * 128; i += stride) {
        int o = i >> 7, cpr = (i >> 3) & 15, j = i & 7;
        int kc = cpr ^ (o & 7);
        int k = (kc << 3) | j;
        w3img[i] = (_Float16)w3[k * 64 + o];
    }
}

// ---------- main fused edge kernel ----------
// 256 threads = 4 waves; 256 edges/block; wave w owns edges [bs+w*64, bs+w*64+64).
// Each wave: 2 passes of 32 edges: L1(fp32)->A-frags, L2 MFMA -> h2 slice (LDS,
// wave-local), L3 MFMA -> h3 slice (f32), then per-wave sorted-run scan.
__device__ __forceinline__ void load_msg(float* msg, int s, int d,
                                         const float* __restrict__ x,
                                         const float* __restrict__ pos)
{
    const float4* xv = reinterpret_cast<const float4*>(x + (size_t)s * 16);
    float4 x0 = xv[0], x1 = xv[1], x2 = xv[2], x3 = xv[3];
    msg[0] = x0.x;  msg[1] = x0.y;  msg[2] = x0.z;  msg[3] = x0.w;
    msg[4] = x1.x;  msg[5] = x1.y;  msg[6] = x1.z;  msg[7] = x1.w;
    msg[8] = x2.x;  msg[9] = x2.y;  msg[10] = x2.z; msg[11] = x2.w;
    msg[12] = x3.x; msg[13] = x3.y; msg[14] = x3.z; msg[15] = x3.w;
    msg[16] = pos[(size_t)s * 3 + 0] - pos[(size_t)d * 3 + 0];
    msg[17] = pos[(size_t)s * 3 + 1] - pos[(size_t)d * 3 + 1];
    msg[18] = pos[(size_t)s * 3 + 2] - pos[(size_t)d * 3 + 2];
}

__global__ __launch_bounds__(256, 1)
void edge_mlp_mfma(const float* __restrict__ x, const float* __restrict__ pos,
                   const float* __restrict__ w1, const float* __restrict__ b1,
                   const _Float16* __restrict__ w2img, const float* __restrict__ b2,
                   const _Float16* __restrict__ w3img, const float* __restrict__ b3,
                   const int2* __restrict__ ep, int E, float* __restrict__ aggf)
{
    __shared__ __align__(16) _Float16 w2s[128 * 64];    // 16 KB
    __shared__ __align__(16) _Float16 w3s[64 * 128];    // 16 KB
    __shared__ __align__(16) float w1s[19 * 64];        // 4.75 KB
    __shared__ __align__(16) float b1s[64], b2s[128], b3s[64];
    __shared__ __align__(16) int2 sd[256];              // 2 KB
    __shared__ __align__(16) _Float16 h2s[4][32 * 128]; // 32 KB (per-wave slices)
    __shared__ __align__(16) float h3s[4][64 * 64];     // 64 KB (per-wave slices)

    const int t  = threadIdx.x;
    const int bs = blockIdx.x * 256;

    // ---- stage weights + edge pairs ----
    {
        const int4* s2 = (const int4*)w2img;
        int4* d2 = (int4*)w2s;
        for (int i = t; i < 1024; i += 256) d2[i] = s2[i];
        const int4* s3 = (const int4*)w3img;
        int4* d3 = (int4*)w3s;
        for (int i = t; i < 1024; i += 256) d3[i] = s3[i];
    }
    for (int i = t; i < 19 * 64; i += 256) w1s[i] = w1[i];
    if (t < 64) { b1s[t] = b1[t]; b3s[t] = b3[t]; }
    if (t < 128) b2s[t] = b2[t];
    sd[t] = ep[min(bs + t, E - 1)];
    __syncthreads();

    const int lane = t & 63;
    const int w    = t >> 6;
    const int g    = lane >> 4;
    const int li   = lane & 15;
    const int W    = bs + w * 64;          // wave's window start in sorted order
    _Float16* h2w = &h2s[w][0];
    float*    h3w = &h3s[w][0];

    #pragma unroll
    for (int p = 0; p < 2; ++p) {
        // ---- layer 1 (fp32) -> A-frags for 2 m-tiles (32 edges) ----
        float msg0[19], msg1[19];
        {
            int2 e0 = sd[w * 64 + p * 32 + li];
            int2 e1 = sd[w * 64 + p * 32 + 16 + li];
            load_msg(msg0, e0.x, e0.y, x, pos);
            load_msg(msg1, e1.x, e1.y, x, pos);
        }
        half8 afr[2][2];
        #pragma unroll
        for (int ks = 0; ks < 2; ++ks) {
            const int ch0 = ks * 32 + g * 8;
            const float4* bv = (const float4*)&b1s[ch0];
            float4 ba = bv[0], bb = bv[1];
            float a0[8] = {ba.x, ba.y, ba.z, ba.w, bb.x, bb.y, bb.z, bb.w};
            float a1[8] = {ba.x, ba.y, ba.z, ba.w, bb.x, bb.y, bb.z, bb.w};
            #pragma unroll
            for (int k = 0; k < 19; ++k) {
                const float4* wr = (const float4*)&w1s[k * 64 + ch0];
                float4 wa = wr[0], wb = wr[1];
                float m0 = msg0[k], m1 = msg1[k];
                a0[0] += m0 * wa.x; a0[1] += m0 * wa.y; a0[2] += m0 * wa.z; a0[3] += m0 * wa.w;
                a0[4] += m0 * wb.x; a0[5] += m0 * wb.y; a0[6] += m0 * wb.z; a0[7] += m0 * wb.w;
                a1[0] += m1 * wa.x; a1[1] += m1 * wa.y; a1[2] += m1 * wa.z; a1[3] += m1 * wa.w;
                a1[4] += m1 * wb.x; a1[5] += m1 * wb.y; a1[6] += m1 * wb.z; a1[7] += m1 * wb.w;
            }
            half8 h0, h1v;
            #pragma unroll
            for (int j = 0; j < 8; ++j) {
                h0[j]  = (_Float16)RELU(a0[j]);
                h1v[j] = (_Float16)RELU(a1[j]);
            }
            afr[0][ks] = h0;
            afr[1][ks] = h1v;
        }

        // ---- layer 2: [32e x 64k] x [64k x 128o] ----
        floatx4 acc2[2][8];
        #pragma unroll
        for (int nf = 0; nf < 8; ++nf) {
            float bv = b2s[nf * 16 + li];
            acc2[0][nf] = (floatx4){bv, bv, bv, bv};
            acc2[1][nf] = (floatx4){bv, bv, bv, bv};
        }
        #pragma unroll
        for (int ks = 0; ks < 2; ++ks) {
            #pragma unroll
            for (int nf = 0; nf < 8; ++nf) {
                const int o = nf * 16 + li;
                const int cpr = (ks * 4 + g) ^ (o & 7);
                half8 bfr = *(const half8*)&w2s[o * 64 + cpr * 8];
                acc2[0][nf] = __builtin_amdgcn_mfma_f32_16x16x32_f16(afr[0][ks], bfr, acc2[0][nf], 0, 0, 0);
                acc2[1][nf] = __builtin_amdgcn_mfma_f32_16x16x32_f16(afr[1][ks], bfr, acc2[1][nf], 0, 0, 0);
            }
        }
        // epilogue: relu -> fp16 -> h2 slice (swizzled), wave-local
        #pragma unroll
        for (int mf = 0; mf < 2; ++mf)
            #pragma unroll
            for (int nf = 0; nf < 8; ++nf)
                #pragma unroll
                for (int r = 0; r < 4; ++r) {
                    const int e2 = mf * 16 + g * 4 + r;
                    const int o  = nf * 16 + li;
                    const int cpr = (o >> 3) ^ (e2 & 7);
                    h2w[e2 * 128 + cpr * 8 + (o & 7)] = (_Float16)RELU(acc2[mf][nf][r]);
                }
        // wave-local LDS visibility (no cross-wave use of this slice)
        asm volatile("s_waitcnt lgkmcnt(0)" ::: "memory");

        // ---- layer 3: [32e x 128k] x [128k x 64o] ----
        floatx4 acc3[2][4];
        #pragma unroll
        for (int nf = 0; nf < 4; ++nf) {
            float bv = b3s[nf * 16 + li];
            acc3[0][nf] = (floatx4){bv, bv, bv, bv};
            acc3[1][nf] = (floatx4){bv, bv, bv, bv};
        }
        #pragma unroll
        for (int ks = 0; ks < 4; ++ks) {
            half8 a2[2], b3f[4];
            #pragma unroll
            for (int mf = 0; mf < 2; ++mf) {
                const int e2 = mf * 16 + li;
                const int cpr = (ks * 4 + g) ^ (e2 & 7);
                a2[mf] = *(const half8*)&h2w[e2 * 128 + cpr * 8];
            }
            #pragma unroll
            for (int nf = 0; nf < 4; ++nf) {
                const int o = nf * 16 + li;
                const int cpr = (ks * 4 + g) ^ (o & 7);
                b3f[nf] = *(const half8*)&w3s[o * 128 + cpr * 8];
            }
            #pragma unroll
            for (int mf = 0; mf < 2; ++mf)
                #pragma unroll
                for (int nf = 0; nf < 4; ++nf)
                    acc3[mf][nf] = __builtin_amdgcn_mfma_f32_16x16x32_f16(a2[mf], b3f[nf], acc3[mf][nf], 0, 0, 0);
        }
        // epilogue: relu -> h3 slice (f32, bank-spread swizzle on col)
        #pragma unroll
        for (int mf = 0; mf < 2; ++mf)
            #pragma unroll
            for (int nf = 0; nf < 4; ++nf)
                #pragma unroll
                for (int r = 0; r < 4; ++r) {
                    const int e3 = p * 32 + mf * 16 + g * 4 + r;
                    const int o  = nf * 16 + li;
                    h3w[e3 * 64 + (o ^ (((e3 >> 2) & 3) << 4))] = RELU(acc3[mf][nf][r]);
                }
    } // p

    asm volatile("s_waitcnt lgkmcnt(0)" ::: "memory");

    // ---- per-wave sorted-run scan over its 64-edge window ----
    const int n = min(64, E - W);
    if (n > 0) {
        const int c = lane;
        const int prevd = (W == 0) ? -2 : ((w > 0) ? sd[w * 64 - 1].y : ep[W - 1].y);
        const int nextd = (W + n >= E) ? -2 : ((w < 3) ? sd[(w + 1) * 64].y : ep[W + 64].y);
        int curd = -1;
        float mv = 0.0f;
        for (int i = 0; i < n; ++i) {
            const int d = sd[w * 64 + i].y;
            const float v = h3w[i * 64 + (c ^ (((i >> 2) & 3) << 4))];
            if (d != curd) {
                if (curd >= 0) {
                    if (curd == prevd || curd == nextd)
                        atomicMax((int*)&aggf[(size_t)curd * 64 + c], __float_as_int(mv));
                    else
                        aggf[(size_t)curd * 64 + c] = mv;
                }
                curd = d;
                mv = v;
            } else {
                mv = fmaxf(mv, v);
            }
        }
        if (curd >= 0) {
            if (curd == prevd || curd == nextd)
                atomicMax((int*)&aggf[(size_t)curd * 64 + c], __float_as_int(mv));
            else
                aggf[(size_t)curd * 64 + c] = mv;
        }
    }
}

// ---------- node MLP: out = relu(agg @ wg + bg) ----------
__global__ __launch_bounds__(256, 4)
void node_out_kernel(const float* __restrict__ agg, const float* __restrict__ wg,
                     const float* __restrict__ bg, float* __restrict__ out, int N)
{
    __shared__ float wgs[64 * 64];
    for (int i = threadIdx.x; i < 64 * 64; i += blockDim.x) wgs[i] = wg[i];
    __syncthreads();

    const int t = blockIdx.x * blockDim.x + threadIdx.x;
    const int nidx = t >> 4;
    const int og = t & 15;
    if (nidx >= N) return;

    const float4* aggv = reinterpret_cast<const float4*>(agg + (size_t)nidx * 64);
    const float4* wgsv = reinterpret_cast<const float4*>(wgs);

    float4 acc = reinterpret_cast<const float4*>(bg)[og];
    #pragma unroll
    for (int kg = 0; kg < 16; ++kg) {
        float4 a = aggv[kg];
        float4 w0 = wgsv[(kg * 4 + 0) * 16 + og];
        float4 w1 = wgsv[(kg * 4 + 1) * 16 + og];
        float4 w2 = wgsv[(kg * 4 + 2) * 16 + og];
        float4 w3 = wgsv[(kg * 4 + 3) * 16 + og];
        acc.x += a.x * w0.x + a.y * w1.x + a.z * w2.x + a.w * w3.x;
        acc.y += a.x * w0.y + a.y * w1.y + a.z * w2.y + a.w * w3.y;
        acc.z += a.x * w0.z + a.y * w1.z + a.z * w2.z + a.w * w3.z;
        acc.w += a.x * w0.w + a.y * w1.w + a.z * w2.w + a.w * w3.w;
    }
    float4 r;
    r.x = RELU(acc.x); r.y = RELU(acc.y); r.z = RELU(acc.z); r.w = RELU(acc.w);
    reinterpret_cast<float4*>(out)[(size_t)nidx * 16 + og] = r;
}

extern "C" void kernel_launch(void* const* d_in, const int* in_sizes, int n_in,
                              void* d_out, int out_size, void* d_ws, size_t ws_size,
                              hipStream_t stream)
{
    const float* x   = (const float*)d_in[0];
    const float* pos = (const float*)d_in[1];
    const float* w1  = (const float*)d_in[2];
    const float* b1  = (const float*)d_in[3];
    const float* w2  = (const float*)d_in[4];
    const float* b2  = (const float*)d_in[5];
    const float* w3  = (const float*)d_in[6];
    const float* b3  = (const float*)d_in[7];
    const float* wg  = (const float*)d_in[8];
    const float* bg  = (const float*)d_in[9];
    const int*   ei  = (const int*)d_in[10];

    const int N = in_sizes[0] / 16;
    const int E = in_sizes[10] / 2;

    // ws layout (int elements)
    int* wsi  = (int*)d_ws;
    int* cnt  = wsi;                           // [102400]
    int* cur  = wsi + 102400;                  // [102400]
    int* bsum = wsi + 204800;                  // [128]
    int2* ep  = (int2*)(wsi + 204928);         // [E]
    int* agg  = wsi + 204928 + 2 * E;          // [N*64] float bits
    _Float16* w2img = (_Float16*)(wsi + 204928 + 2 * E + 6400000);  // [8192]
    _Float16* w3img = w2img + 8192;                                  // [8192]

    hipMemsetAsync(cnt, 0, (size_t)N * sizeof(int), stream);
    hipMemsetAsync(agg, 0, (size_t)N * 64 * sizeof(int), stream);

    const int eb = (E + 255) / 256;
    const int NB = (N + 1023) / 1024;
    prep_weights<<<8, 256, 0, stream>>>(w2, w3, w2img, w3img);
    count_kernel<<<eb, 256, 0, stream>>>(ei, E, cnt);
    scan1_kernel<<<NB, 1024, 0, stream>>>(cnt, cur, bsum, N);
    scan2_kernel<<<1, 128, 0, stream>>>(bsum, NB);
    scan3_kernel<<<(N + 255) / 256, 256, 0, stream>>>(cur, bsum, N);
    scatter_kernel<<<eb, 256, 0, stream>>>(ei, E, cur, ep);
    edge_mlp_mfma<<<(E + 255) / 256, 256, 0, stream>>>(
        x, pos, w1, b1, w2img, b2, w3img, b3, ep, E, (float*)agg);
    node_out_kernel<<<(N * 16 + 255) / 256, 256, 0, stream>>>(
        (const float*)agg, wg, bg, (float*)d_out, N);
}

// Round 5
// 523.186 us; speedup vs baseline: 8.6297x; 1.3490x over previous
//
#include <hip/hip_runtime.h>

// PointNetLayer round 5: LDS diet (73.5KB -> 2 blocks/CU). Per-pass h3 scan with
// carried run state; L2 double-pumped over 64-col halves; h2/h3 overlaid in one
// 8KB/wave scratch (wave-local waitcnt fences). Single merged memset.

typedef __attribute__((ext_vector_type(8))) _Float16 half8;
typedef __attribute__((ext_vector_type(4))) float floatx4;

#define RELU(v) fmaxf((v), 0.0f)
#define LDS_FENCE() asm volatile("s_waitcnt lgkmcnt(0)" ::: "memory")

// ---------- sort pass 1: histogram ----------
__global__ void count_kernel(const int* __restrict__ ei, int E, int* __restrict__ cnt)
{
    int e = blockIdx.x * blockDim.x + threadIdx.x;
    if (e < E) atomicAdd(&cnt[ei[E + e]], 1);
}

// ---------- sort pass 2: parallel exclusive scan (3 kernels) ----------
__global__ __launch_bounds__(1024)
void scan1_kernel(const int* __restrict__ cnt, int* __restrict__ cur,
                  int* __restrict__ bsum, int N)
{
    __shared__ int sh[1024];
    const int t = threadIdx.x, b = blockIdx.x;
    const int idx = b * 1024 + t;
    int v = (idx < N) ? cnt[idx] : 0;
    sh[t] = v;
    __syncthreads();
    for (int off = 1; off < 1024; off <<= 1) {
        int o = (t >= off) ? sh[t - off] : 0;
        __syncthreads();
        sh[t] += o;
        __syncthreads();
    }
    if (idx < N) cur[idx] = sh[t] - v;
    if (t == 1023) bsum[b] = sh[t];
}

__global__ __launch_bounds__(128)
void scan2_kernel(int* __restrict__ bsum, int NB)
{
    __shared__ int sh[128];
    const int t = threadIdx.x;
    int v = (t < NB) ? bsum[t] : 0;
    sh[t] = v;
    __syncthreads();
    for (int off = 1; off < 128; off <<= 1) {
        int o = (t >= off) ? sh[t - off] : 0;
        __syncthreads();
        sh[t] += o;
        __syncthreads();
    }
    if (t < NB) bsum[t] = sh[t] - v;
}

__global__ void scan3_kernel(int* __restrict__ cur, const int* __restrict__ bsum, int N)
{
    int idx = blockIdx.x * blockDim.x + threadIdx.x;
    if (idx < N) cur[idx] += bsum[idx >> 10];
}

// ---------- sort pass 3: scatter (s,d) as int2 ----------
__global__ void scatter_kernel(const int* __restrict__ ei, int E, int* __restrict__ cur,
                               int2* __restrict__ ep)
{
    int e = blockIdx.x * blockDim.x + threadIdx.x;
    if (e >= E) return;
    int s = ei[e], d = ei[E + e];
    int p = atomicAdd(&cur[d], 1);
    ep[p] = make_int2(s, d);
}

// ---------- weight image prep (fp16, XOR chunk swizzle) ----------
// w2img: [o=0..127][cpr=0..7][j=0..7]  element = w2[k][o], k = (cpr^(o&7))*8 + j
// w3img: [o=0..63][cpr=0..15][j=0..7]  element = w3[k][o], k = ((cpr^(o&7)))*8 + j
__global__ void prep_weights(const float* __restrict__ w2, const float* __restrict__ w3,
                             _Float16* __restrict__ w2img, _Float16* __restrict__ w3img)
{
    int t = blockIdx.x * blockDim.x + threadIdx.x;
    int stride = gridDim.x * blockDim.x;
    for (int i = t; i < 128 * 64; i += stride) {
        int o = i >> 6, cpr = (i >> 3) & 7, j = i & 7;
        int k = ((cpr ^ (o & 7)) << 3) | j;
        w2img[i] = (_Float16)w2[k * 128 + o];
    }
    for (int i = t; i < 64 * 128; i += stride) {
        int o = i >> 7, cpr = (i >> 3) & 15, j = i & 7;
        int kc = cpr ^ (o & 7);
        int k = (kc << 3) | j;
        w3img[i] = (_Float16)w3[k * 64 + o];
    }
}

__device__ __forceinline__ void load_msg(float* msg, int s, int d,
                                         const float* __restrict__ x,
                                         const float* __restrict__ pos)
{
    const float4* xv = reinterpret_cast<const float4*>(x + (size_t)s * 16);
    float4 x0 = xv[0], x1 = xv[1], x2 = xv[2], x3 = xv[3];
    msg[0] = x0.x;  msg[1] = x0.y;  msg[2] = x0.z;  msg[3] = x0.w;
    msg[4] = x1.x;  msg[5] = x1.y;  msg[6] = x1.z;  msg[7] = x1.w;
    msg[8] = x2.x;  msg[9] = x2.y;  msg[10] = x2.z; msg[11] = x2.w;
    msg[12] = x3.x; msg[13] = x3.y; msg[14] = x3.z; msg[15] = x3.w;
    msg[16] = pos[(size_t)s * 3 + 0] - pos[(size_t)d * 3 + 0];
    msg[17] = pos[(size_t)s * 3 + 1] - pos[(size_t)d * 3 + 1];
    msg[18] = pos[(size_t)s * 3 + 2] - pos[(size_t)d * 3 + 2];
}

// ---------- main fused edge kernel ----------
// 256 thr = 4 waves, 256 edges/block, wave owns 64 edges in sorted order.
// Per 32-edge pass: L1 fp32 -> A-frags; L2 MFMA double-pumped over 64-col halves
// (h2 4KB in scratch); L3 MFMA accumulates; h3 (8KB, overlays h2) -> per-pass
// sorted-run scan with carried (curd,mv). LDS total ~73.5KB -> 2 blocks/CU.
__global__ __launch_bounds__(256, 2)
void edge_mlp_mfma(const float* __restrict__ x, const float* __restrict__ pos,
                   const float* __restrict__ w1, const float* __restrict__ b1,
                   const _Float16* __restrict__ w2img, const float* __restrict__ b2,
                   const _Float16* __restrict__ w3img, const float* __restrict__ b3,
                   const int2* __restrict__ ep, int E, float* __restrict__ aggf)
{
    __shared__ __align__(16) _Float16 w2s[128 * 64];    // 16 KB
    __shared__ __align__(16) _Float16 w3s[64 * 128];    // 16 KB
    __shared__ __align__(16) float w1s[19 * 64];        // 4.75 KB
    __shared__ __align__(16) float b1s[64], b2s[128], b3s[64];
    __shared__ __align__(16) int2 sd[256];              // 2 KB
    __shared__ __align__(16) float scratch[4][2048];    // 8 KB per wave (h2 fp16 / h3 f32 overlay)

    const int t  = threadIdx.x;
    const int bs = blockIdx.x * 256;

    // ---- stage weights + edge pairs ----
    {
        const int4* s2 = (const int4*)w2img;
        int4* d2 = (int4*)w2s;
        for (int i = t; i < 1024; i += 256) d2[i] = s2[i];
        const int4* s3 = (const int4*)w3img;
        int4* d3 = (int4*)w3s;
        for (int i = t; i < 1024; i += 256) d3[i] = s3[i];
    }
    for (int i = t; i < 19 * 64; i += 256) w1s[i] = w1[i];
    if (t < 64) { b1s[t] = b1[t]; b3s[t] = b3[t]; }
    if (t < 128) b2s[t] = b2[t];
    sd[t] = ep[min(bs + t, E - 1)];
    __syncthreads();

    const int lane = t & 63;
    const int w    = t >> 6;
    const int g    = lane >> 4;
    const int li   = lane & 15;
    const int W    = bs + w * 64;
    float*    h3w = &scratch[w][0];
    _Float16* h2h = (_Float16*)&scratch[w][0];

    const int n = min(64, E - W);   // edges this wave owns (may be <=0)
    const int c = lane;
    int prevd = -2, nextd = -2;
    if (n > 0) {
        prevd = (W == 0) ? -2 : ((w > 0) ? sd[w * 64 - 1].y : ep[W - 1].y);
        nextd = (W + n >= E) ? -2 : ((w < 3) ? sd[(w + 1) * 64].y : ep[W + 64].y);
    }
    int curd = -1;
    float mv = 0.0f;

    #pragma unroll
    for (int p = 0; p < 2; ++p) {
        // ---- layer 1 (fp32) -> A-frags for 2 m-tiles (32 edges) ----
        float msg0[19], msg1[19];
        {
            int2 e0 = sd[w * 64 + p * 32 + li];
            int2 e1 = sd[w * 64 + p * 32 + 16 + li];
            load_msg(msg0, e0.x, e0.y, x, pos);
            load_msg(msg1, e1.x, e1.y, x, pos);
        }
        half8 afr[2][2];
        #pragma unroll
        for (int ks = 0; ks < 2; ++ks) {
            const int ch0 = ks * 32 + g * 8;
            const float4* bv = (const float4*)&b1s[ch0];
            float4 ba = bv[0], bb = bv[1];
            float a0[8] = {ba.x, ba.y, ba.z, ba.w, bb.x, bb.y, bb.z, bb.w};
            float a1[8] = {ba.x, ba.y, ba.z, ba.w, bb.x, bb.y, bb.z, bb.w};
            #pragma unroll
            for (int k = 0; k < 19; ++k) {
                const float4* wr = (const float4*)&w1s[k * 64 + ch0];
                float4 wa = wr[0], wb = wr[1];
                float m0 = msg0[k], m1 = msg1[k];
                a0[0] += m0 * wa.x; a0[1] += m0 * wa.y; a0[2] += m0 * wa.z; a0[3] += m0 * wa.w;
                a0[4] += m0 * wb.x; a0[5] += m0 * wb.y; a0[6] += m0 * wb.z; a0[7] += m0 * wb.w;
                a1[0] += m1 * wa.x; a1[1] += m1 * wa.y; a1[2] += m1 * wa.z; a1[3] += m1 * wa.w;
                a1[4] += m1 * wb.x; a1[5] += m1 * wb.y; a1[6] += m1 * wb.z; a1[7] += m1 * wb.w;
            }
            half8 h0, h1v;
            #pragma unroll
            for (int j = 0; j < 8; ++j) {
                h0[j]  = (_Float16)RELU(a0[j]);
                h1v[j] = (_Float16)RELU(a1[j]);
            }
            afr[0][ks] = h0;
            afr[1][ks] = h1v;
        }

        // ---- L2 (double-pumped 64-col halves) + L3 accumulate ----
        floatx4 acc3[2][4];
        #pragma unroll
        for (int nf = 0; nf < 4; ++nf) {
            float bv = b3s[nf * 16 + li];
            acc3[0][nf] = (floatx4){bv, bv, bv, bv};
            acc3[1][nf] = (floatx4){bv, bv, bv, bv};
        }

        #pragma unroll
        for (int hf = 0; hf < 2; ++hf) {
            // L2 half: cols [hf*64, hf*64+64)
            floatx4 acc2[2][4];
            #pragma unroll
            for (int nf = 0; nf < 4; ++nf) {
                float bv = b2s[hf * 64 + nf * 16 + li];
                acc2[0][nf] = (floatx4){bv, bv, bv, bv};
                acc2[1][nf] = (floatx4){bv, bv, bv, bv};
            }
            #pragma unroll
            for (int ks = 0; ks < 2; ++ks) {
                #pragma unroll
                for (int nf = 0; nf < 4; ++nf) {
                    const int o = hf * 64 + nf * 16 + li;
                    const int cpr = (ks * 4 + g) ^ (o & 7);
                    half8 bfr = *(const half8*)&w2s[o * 64 + cpr * 8];
                    acc2[0][nf] = __builtin_amdgcn_mfma_f32_16x16x32_f16(afr[0][ks], bfr, acc2[0][nf], 0, 0, 0);
                    acc2[1][nf] = __builtin_amdgcn_mfma_f32_16x16x32_f16(afr[1][ks], bfr, acc2[1][nf], 0, 0, 0);
                }
            }
            // WAR fence: all prior reads of this scratch region must be complete
            LDS_FENCE();
            // epilogue: relu -> fp16 -> h2 (4KB, local cols 0..63)
            #pragma unroll
            for (int mf = 0; mf < 2; ++mf)
                #pragma unroll
                for (int nf = 0; nf < 4; ++nf)
                    #pragma unroll
                    for (int r = 0; r < 4; ++r) {
                        const int e2 = mf * 16 + g * 4 + r;
                        const int ol = nf * 16 + li;
                        const int cpr = (ol >> 3) ^ (e2 & 7);
                        h2h[e2 * 64 + cpr * 8 + (ol & 7)] = (_Float16)RELU(acc2[mf][nf][r]);
                    }
            LDS_FENCE();
            __builtin_amdgcn_sched_barrier(0);
            // L3 partial: global k chunks ksg = hf*2 + ks_l
            #pragma unroll
            for (int ks_l = 0; ks_l < 2; ++ks_l) {
                const int ksg = hf * 2 + ks_l;
                half8 a2[2], b3f[4];
                #pragma unroll
                for (int mf = 0; mf < 2; ++mf) {
                    const int e2 = mf * 16 + li;
                    const int ca = (ks_l * 4 + g) ^ (e2 & 7);
                    a2[mf] = *(const half8*)&h2h[e2 * 64 + ca * 8];
                }
                #pragma unroll
                for (int nf = 0; nf < 4; ++nf) {
                    const int o = nf * 16 + li;
                    const int cb = (ksg * 4 + g) ^ (o & 7);
                    b3f[nf] = *(const half8*)&w3s[o * 128 + cb * 8];
                }
                #pragma unroll
                for (int mf = 0; mf < 2; ++mf)
                    #pragma unroll
                    for (int nf = 0; nf < 4; ++nf)
                        acc3[mf][nf] = __builtin_amdgcn_mfma_f32_16x16x32_f16(a2[mf], b3f[nf], acc3[mf][nf], 0, 0, 0);
            }
        } // hf

        // ---- h3 epilogue (overlays h2 region; 8KB) ----
        LDS_FENCE();
        #pragma unroll
        for (int mf = 0; mf < 2; ++mf)
            #pragma unroll
            for (int nf = 0; nf < 4; ++nf)
                #pragma unroll
                for (int r = 0; r < 4; ++r) {
                    const int e3 = mf * 16 + g * 4 + r;   // local 0..31
                    const int o  = nf * 16 + li;
                    h3w[e3 * 64 + (o ^ (((e3 >> 2) & 3) << 4))] = RELU(acc3[mf][nf][r]);
                }
        LDS_FENCE();
        __builtin_amdgcn_sched_barrier(0);

        // ---- per-pass sorted-run scan (carried state) ----
        {
            const int lim = min(32, n - p * 32);
            for (int i = 0; i < lim; ++i) {
                const int d = sd[w * 64 + p * 32 + i].y;
                const float v = h3w[i * 64 + (c ^ (((i >> 2) & 3) << 4))];
                if (d != curd) {
                    if (curd >= 0) {
                        if (curd == prevd || curd == nextd)
                            atomicMax((int*)&aggf[(size_t)curd * 64 + c], __float_as_int(mv));
                        else
                            aggf[(size_t)curd * 64 + c] = mv;
                    }
                    curd = d;
                    mv = v;
                } else {
                    mv = fmaxf(mv, v);
                }
            }
        }
        LDS_FENCE();   // scan reads complete before next pass reuses scratch
    } // p

    if (curd >= 0) {
        if (curd == prevd || curd == nextd)
            atomicMax((int*)&aggf[(size_t)curd * 64 + c], __float_as_int(mv));
        else
            aggf[(size_t)curd * 64 + c] = mv;
    }
}

// ---------- node MLP: out = relu(agg @ wg + bg) ----------
__global__ __launch_bounds__(256, 4)
void node_out_kernel(const float* __restrict__ agg, const float* __restrict__ wg,
                     const float* __restrict__ bg, float* __restrict__ out, int N)
{
    __shared__ float wgs[64 * 64];
    for (int i = threadIdx.x; i < 64 * 64; i += blockDim.x) wgs[i] = wg[i];
    __syncthreads();

    const int t = blockIdx.x * blockDim.x + threadIdx.x;
    const int nidx = t >> 4;
    const int og = t & 15;
    if (nidx >= N) return;

    const float4* aggv = reinterpret_cast<const float4*>(agg + (size_t)nidx * 64);
    const float4* wgsv = reinterpret_cast<const float4*>(wgs);

    float4 acc = reinterpret_cast<const float4*>(bg)[og];
    #pragma unroll
    for (int kg = 0; kg < 16; ++kg) {
        float4 a = aggv[kg];
        float4 w0 = wgsv[(kg * 4 + 0) * 16 + og];
        float4 w1 = wgsv[(kg * 4 + 1) * 16 + og];
        float4 w2 = wgsv[(kg * 4 + 2) * 16 + og];
        float4 w3 = wgsv[(kg * 4 + 3) * 16 + og];
        acc.x += a.x * w0.x + a.y * w1.x + a.z * w2.x + a.w * w3.x;
        acc.y += a.x * w0.y + a.y * w1.y + a.z * w2.y + a.w * w3.y;
        acc.z += a.x * w0.z + a.y * w1.z + a.z * w2.z + a.w * w3.z;
        acc.w += a.x * w0.w + a.y * w1.w + a.z * w2.w + a.w * w3.w;
    }
    float4 r;
    r.x = RELU(acc.x); r.y = RELU(acc.y); r.z = RELU(acc.z); r.w = RELU(acc.w);
    reinterpret_cast<float4*>(out)[(size_t)nidx * 16 + og] = r;
}

extern "C" void kernel_launch(void* const* d_in, const int* in_sizes, int n_in,
                              void* d_out, int out_size, void* d_ws, size_t ws_size,
                              hipStream_t stream)
{
    const float* x   = (const float*)d_in[0];
    const float* pos = (const float*)d_in[1];
    const float* w1  = (const float*)d_in[2];
    const float* b1  = (const float*)d_in[3];
    const float* w2  = (const float*)d_in[4];
    const float* b2  = (const float*)d_in[5];
    const float* w3  = (const float*)d_in[6];
    const float* b3  = (const float*)d_in[7];
    const float* wg  = (const float*)d_in[8];
    const float* bg  = (const float*)d_in[9];
    const int*   ei  = (const int*)d_in[10];

    const int N = in_sizes[0] / 16;
    const int E = in_sizes[10] / 2;

    // ws layout (int elements): [cnt N][agg N*64][cur N][bsum 128][ep 2E][images]
    int* wsi  = (int*)d_ws;
    int* cnt  = wsi;                               // [N]
    int* agg  = wsi + N;                           // [N*64]
    int* cur  = wsi + N + N * 64;                  // [N]
    int* bsum = wsi + N * 66;                      // [128]
    int2* ep  = (int2*)(wsi + N * 66 + 128);       // [E]
    _Float16* w2img = (_Float16*)(wsi + N * 66 + 128 + 2 * E);  // [8192]
    _Float16* w3img = w2img + 8192;                              // [8192]

    // single merged memset over cnt+agg (contiguous)
    hipMemsetAsync(cnt, 0, (size_t)N * 65 * sizeof(int), stream);

    const int eb = (E + 255) / 256;
    const int NB = (N + 1023) / 1024;
    prep_weights<<<8, 256, 0, stream>>>(w2, w3, w2img, w3img);
    count_kernel<<<eb, 256, 0, stream>>>(ei, E, cnt);
    scan1_kernel<<<NB, 1024, 0, stream>>>(cnt, cur, bsum, N);
    scan2_kernel<<<1, 128, 0, stream>>>(bsum, NB);
    scan3_kernel<<<(N + 255) / 256, 256, 0, stream>>>(cur, bsum, N);
    scatter_kernel<<<eb, 256, 0, stream>>>(ei, E, cur, ep);
    edge_mlp_mfma<<<(E + 255) / 256, 256, 0, stream>>>(
        x, pos, w1, b1, w2img, b2, w3img, b3, ep, E, (float*)agg);
    node_out_kernel<<<(N * 16 + 255) / 256, 256, 0, stream>>>(
        (const float*)agg, wg, bg, (float*)d_out, N);
}

// Round 6
// 462.874 us; speedup vs baseline: 9.7541x; 1.1303x over previous
//
#include <hip/hip_runtime.h>

// PointNetLayer round 6: L1 moved onto MFMA (k padded 19->32), msg gathered once
// per edge (lanes<32) and staged to LDS fp16; h1 LDS image feeds L2 A-frags;
// scan run-compares scalarized via readfirstlane. Scratch overlay keeps 8KB/wave.

typedef __attribute__((ext_vector_type(8))) _Float16 half8;
typedef __attribute__((ext_vector_type(4))) float floatx4;

#define RELU(v) fmaxf((v), 0.0f)
#define LDS_FENCE() asm volatile("s_waitcnt lgkmcnt(0)" ::: "memory")

// ---------- sort pass 1: histogram ----------
__global__ void count_kernel(const int* __restrict__ ei, int E, int* __restrict__ cnt)
{
    int e = blockIdx.x * blockDim.x + threadIdx.x;
    if (e < E) atomicAdd(&cnt[ei[E + e]], 1);
}

// ---------- sort pass 2: parallel exclusive scan (3 kernels) ----------
__global__ __launch_bounds__(1024)
void scan1_kernel(const int* __restrict__ cnt, int* __restrict__ cur,
                  int* __restrict__ bsum, int N)
{
    __shared__ int sh[1024];
    const int t = threadIdx.x, b = blockIdx.x;
    const int idx = b * 1024 + t;
    int v = (idx < N) ? cnt[idx] : 0;
    sh[t] = v;
    __syncthreads();
    for (int off = 1; off < 1024; off <<= 1) {
        int o = (t >= off) ? sh[t - off] : 0;
        __syncthreads();
        sh[t] += o;
        __syncthreads();
    }
    if (idx < N) cur[idx] = sh[t] - v;
    if (t == 1023) bsum[b] = sh[t];
}

__global__ __launch_bounds__(128)
void scan2_kernel(int* __restrict__ bsum, int NB)
{
    __shared__ int sh[128];
    const int t = threadIdx.x;
    int v = (t < NB) ? bsum[t] : 0;
    sh[t] = v;
    __syncthreads();
    for (int off = 1; off < 128; off <<= 1) {
        int o = (t >= off) ? sh[t - off] : 0;
        __syncthreads();
        sh[t] += o;
        __syncthreads();
    }
    if (t < NB) bsum[t] = sh[t] - v;
}

__global__ void scan3_kernel(int* __restrict__ cur, const int* __restrict__ bsum, int N)
{
    int idx = blockIdx.x * blockDim.x + threadIdx.x;
    if (idx < N) cur[idx] += bsum[idx >> 10];
}

// ---------- sort pass 3: scatter (s,d) as int2 ----------
__global__ void scatter_kernel(const int* __restrict__ ei, int E, int* __restrict__ cur,
                               int2* __restrict__ ep)
{
    int e = blockIdx.x * blockDim.x + threadIdx.x;
    if (e >= E) return;
    int s = ei[e], d = ei[E + e];
    int p = atomicAdd(&cur[d], 1);
    ep[p] = make_int2(s, d);
}

// ---------- weight image prep (fp16, XOR chunk swizzle) ----------
// w2img: [o=0..127][cpr=0..7][j=0..7]  element = w2[k][o], k = (cpr^(o&7))*8 + j
// w3img: [o=0..63][cpr=0..15][j=0..7]  element = w3[k][o], k = ((cpr^(o&7)))*8 + j
// w1img: [o=0..63][c=0..3][j=0..7]     element = w1[k][o], k = (c^(o&3))*8 + j, 0 if k>=19
__global__ void prep_weights(const float* __restrict__ w1, const float* __restrict__ w2,
                             const float* __restrict__ w3,
                             _Float16* __restrict__ w1img, _Float16* __restrict__ w2img,
                             _Float16* __restrict__ w3img)
{
    int t = blockIdx.x * blockDim.x + threadIdx.x;
    int stride = gridDim.x * blockDim.x;
    for (int i = t; i < 128 * 64; i += stride) {
        int o = i >> 6, cpr = (i >> 3) & 7, j = i & 7;
        int k = ((cpr ^ (o & 7)) << 3) | j;
        w2img[i] = (_Float16)w2[k * 128 + o];
    }
    for (int i = t; i < 64 * 128; i += stride) {
        int o = i >> 7, cpr = (i >> 3) & 15, j = i & 7;
        int kc = cpr ^ (o & 7);
        int k = (kc << 3) | j;
        w3img[i] = (_Float16)w3[k * 64 + o];
    }
    for (int i = t; i < 64 * 32; i += stride) {
        int o = i >> 5, c = (i >> 3) & 3, j = i & 7;
        int k = ((c ^ (o & 3)) << 3) | j;
        w1img[i] = (k < 19) ? (_Float16)w1[k * 64 + o] : (_Float16)0.0f;
    }
}

__device__ __forceinline__ void load_msg(float* msg, int s, int d,
                                         const float* __restrict__ x,
                                         const float* __restrict__ pos)
{
    const float4* xv = reinterpret_cast<const float4*>(x + (size_t)s * 16);
    float4 x0 = xv[0], x1 = xv[1], x2 = xv[2], x3 = xv[3];
    msg[0] = x0.x;  msg[1] = x0.y;  msg[2] = x0.z;  msg[3] = x0.w;
    msg[4] = x1.x;  msg[5] = x1.y;  msg[6] = x1.z;  msg[7] = x1.w;
    msg[8] = x2.x;  msg[9] = x2.y;  msg[10] = x2.z; msg[11] = x2.w;
    msg[12] = x3.x; msg[13] = x3.y; msg[14] = x3.z; msg[15] = x3.w;
    msg[16] = pos[(size_t)s * 3 + 0] - pos[(size_t)d * 3 + 0];
    msg[17] = pos[(size_t)s * 3 + 1] - pos[(size_t)d * 3 + 1];
    msg[18] = pos[(size_t)s * 3 + 2] - pos[(size_t)d * 3 + 2];
}

// ---------- main fused edge kernel ----------
// 256 thr = 4 waves, 256 edges/block, wave owns 64 edges (2 passes of 32).
// Per pass: msg staged fp16 (lanes<32, 1 edge each) -> L1 MFMA -> h1 LDS image ->
// L2 MFMA double-pumped -> L3 MFMA -> h3 -> scalarized sorted-run scan.
// Scratch overlay (8KB/wave): msg[0,2K) ; h1[4K,8K) ; h2[0,4K) ; h3[0,8K).
__global__ __launch_bounds__(256, 2)
void edge_mlp_mfma(const float* __restrict__ x, const float* __restrict__ pos,
                   const _Float16* __restrict__ w1img, const float* __restrict__ b1,
                   const _Float16* __restrict__ w2img, const float* __restrict__ b2,
                   const _Float16* __restrict__ w3img, const float* __restrict__ b3,
                   const int2* __restrict__ ep, int E, float* __restrict__ aggf)
{
    __shared__ __align__(16) _Float16 w2s[128 * 64];    // 16 KB
    __shared__ __align__(16) _Float16 w3s[64 * 128];    // 16 KB
    __shared__ __align__(16) _Float16 w1s[64 * 32];     // 4 KB
    __shared__ __align__(16) float b1s[64], b2s[128], b3s[64];
    __shared__ __align__(16) int2 sd[256];              // 2 KB
    __shared__ __align__(16) float scratch[4][2048];    // 8 KB per wave

    const int t  = threadIdx.x;
    const int bs = blockIdx.x * 256;

    // ---- stage weights + edge pairs ----
    {
        const int4* s2 = (const int4*)w2img;
        int4* d2 = (int4*)w2s;
        for (int i = t; i < 1024; i += 256) d2[i] = s2[i];
        const int4* s3 = (const int4*)w3img;
        int4* d3 = (int4*)w3s;
        for (int i = t; i < 1024; i += 256) d3[i] = s3[i];
        const int4* s1 = (const int4*)w1img;
        int4* d1 = (int4*)w1s;
        if (t < 256) d1[t] = s1[t];
    }
    if (t < 64) { b1s[t] = b1[t]; b3s[t] = b3[t]; }
    if (t < 128) b2s[t] = b2[t];
    sd[t] = ep[min(bs + t, E - 1)];
    __syncthreads();

    const int lane = t & 63;
    const int w    = t >> 6;
    const int g    = lane >> 4;
    const int li   = lane & 15;
    const int W    = bs + w * 64;
    float*    h3w  = &scratch[w][0];
    _Float16* msgh = (_Float16*)&scratch[w][0];      // [32e][4c][8j] fp16, 2KB
    _Float16* h2h  = (_Float16*)&scratch[w][0];      // [32e][8c][8j] fp16, 4KB
    _Float16* h1s  = (_Float16*)&scratch[w][1024];   // [32e][8c][8j] fp16, 4KB

    const int n = min(64, E - W);
    const int c = lane;
    int prevd = -2, nextd = -2;
    if (n > 0) {
        prevd = (W == 0) ? -2 : __builtin_amdgcn_readfirstlane((w > 0) ? sd[w * 64 - 1].y : ep[W - 1].y);
        nextd = (W + n >= E) ? -2 : __builtin_amdgcn_readfirstlane((w < 3) ? sd[(w + 1) * 64].y : ep[W + 64].y);
    }
    int curd = -1;
    float mv = 0.0f;

    #pragma unroll
    for (int p = 0; p < 2; ++p) {
        // ---- msg staging: lanes<32 gather one edge each, cvt fp16, swizzled store ----
        if (lane < 32) {
            const int el = lane;
            int2 e0 = sd[w * 64 + p * 32 + el];
            float m[19];
            load_msg(m, e0.x, e0.y, x, pos);
            _Float16 hv[32];
            #pragma unroll
            for (int k = 0; k < 19; ++k) hv[k] = (_Float16)m[k];
            #pragma unroll
            for (int k = 19; k < 32; ++k) hv[k] = (_Float16)0.0f;
            const int sw = (el >> 1) & 3;
            #pragma unroll
            for (int cch = 0; cch < 4; ++cch) {
                half8 hh;
                #pragma unroll
                for (int j = 0; j < 8; ++j) hh[j] = hv[cch * 8 + j];
                *(half8*)&msgh[el * 32 + (cch ^ sw) * 8] = hh;
            }
        }
        LDS_FENCE();
        __builtin_amdgcn_sched_barrier(0);

        // ---- layer 1 MFMA: [32e x 32k] x [32k x 64o] ----
        {
            half8 w1f[4];
            #pragma unroll
            for (int nf = 0; nf < 4; ++nf) {
                const int o = nf * 16 + li;
                w1f[nf] = *(const half8*)&w1s[o * 32 + (g ^ (o & 3)) * 8];
            }
            floatx4 acc1[2][4];
            #pragma unroll
            for (int nf = 0; nf < 4; ++nf) {
                float bv = b1s[nf * 16 + li];
                acc1[0][nf] = (floatx4){bv, bv, bv, bv};
                acc1[1][nf] = (floatx4){bv, bv, bv, bv};
            }
            #pragma unroll
            for (int mf = 0; mf < 2; ++mf) {
                const int el = mf * 16 + li;
                half8 af = *(const half8*)&msgh[el * 32 + (g ^ ((el >> 1) & 3)) * 8];
                #pragma unroll
                for (int nf = 0; nf < 4; ++nf)
                    acc1[mf][nf] = __builtin_amdgcn_mfma_f32_16x16x32_f16(af, w1f[nf], acc1[mf][nf], 0, 0, 0);
            }
            LDS_FENCE();   // msg reads done (h1 writes go to disjoint region; keep order tight)
            // h1 epilogue: relu -> fp16 -> h1s image (A-frag layout for L2)
            #pragma unroll
            for (int mf = 0; mf < 2; ++mf)
                #pragma unroll
                for (int nf = 0; nf < 4; ++nf)
                    #pragma unroll
                    for (int r = 0; r < 4; ++r) {
                        const int e2 = mf * 16 + g * 4 + r;
                        const int o  = nf * 16 + li;
                        const int cpr = (o >> 3) ^ (e2 & 7);
                        h1s[e2 * 64 + cpr * 8 + (o & 7)] = (_Float16)RELU(acc1[mf][nf][r]);
                    }
        }
        LDS_FENCE();
        __builtin_amdgcn_sched_barrier(0);

        // ---- load L2 A-frags from h1s ----
        half8 afr[2][2];
        #pragma unroll
        for (int ks = 0; ks < 2; ++ks)
            #pragma unroll
            for (int mf = 0; mf < 2; ++mf) {
                const int e2 = mf * 16 + li;
                const int cpr = (ks * 4 + g) ^ (e2 & 7);
                afr[mf][ks] = *(const half8*)&h1s[e2 * 64 + cpr * 8];
            }

        // ---- L2 (double-pumped 64-col halves) + L3 accumulate ----
        floatx4 acc3[2][4];
        #pragma unroll
        for (int nf = 0; nf < 4; ++nf) {
            float bv = b3s[nf * 16 + li];
            acc3[0][nf] = (floatx4){bv, bv, bv, bv};
            acc3[1][nf] = (floatx4){bv, bv, bv, bv};
        }

        #pragma unroll
        for (int hf = 0; hf < 2; ++hf) {
            floatx4 acc2[2][4];
            #pragma unroll
            for (int nf = 0; nf < 4; ++nf) {
                float bv = b2s[hf * 64 + nf * 16 + li];
                acc2[0][nf] = (floatx4){bv, bv, bv, bv};
                acc2[1][nf] = (floatx4){bv, bv, bv, bv};
            }
            #pragma unroll
            for (int ks = 0; ks < 2; ++ks) {
                #pragma unroll
                for (int nf = 0; nf < 4; ++nf) {
                    const int o = hf * 64 + nf * 16 + li;
                    const int cpr = (ks * 4 + g) ^ (o & 7);
                    half8 bfr = *(const half8*)&w2s[o * 64 + cpr * 8];
                    acc2[0][nf] = __builtin_amdgcn_mfma_f32_16x16x32_f16(afr[0][ks], bfr, acc2[0][nf], 0, 0, 0);
                    acc2[1][nf] = __builtin_amdgcn_mfma_f32_16x16x32_f16(afr[1][ks], bfr, acc2[1][nf], 0, 0, 0);
                }
            }
            LDS_FENCE();   // WAR: prior reads of h2 region (hf=0) / msg reads complete
            #pragma unroll
            for (int mf = 0; mf < 2; ++mf)
                #pragma unroll
                for (int nf = 0; nf < 4; ++nf)
                    #pragma unroll
                    for (int r = 0; r < 4; ++r) {
                        const int e2 = mf * 16 + g * 4 + r;
                        const int ol = nf * 16 + li;
                        const int cpr = (ol >> 3) ^ (e2 & 7);
                        h2h[e2 * 64 + cpr * 8 + (ol & 7)] = (_Float16)RELU(acc2[mf][nf][r]);
                    }
            LDS_FENCE();
            __builtin_amdgcn_sched_barrier(0);
            #pragma unroll
            for (int ks_l = 0; ks_l < 2; ++ks_l) {
                const int ksg = hf * 2 + ks_l;
                half8 a2[2], b3f[4];
                #pragma unroll
                for (int mf = 0; mf < 2; ++mf) {
                    const int e2 = mf * 16 + li;
                    const int ca = (ks_l * 4 + g) ^ (e2 & 7);
                    a2[mf] = *(const half8*)&h2h[e2 * 64 + ca * 8];
                }
                #pragma unroll
                for (int nf = 0; nf < 4; ++nf) {
                    const int o = nf * 16 + li;
                    const int cb = (ksg * 4 + g) ^ (o & 7);
                    b3f[nf] = *(const half8*)&w3s[o * 128 + cb * 8];
                }
                #pragma unroll
                for (int mf = 0; mf < 2; ++mf)
                    #pragma unroll
                    for (int nf = 0; nf < 4; ++nf)
                        acc3[mf][nf] = __builtin_amdgcn_mfma_f32_16x16x32_f16(a2[mf], b3f[nf], acc3[mf][nf], 0, 0, 0);
            }
        } // hf

        // ---- h3 epilogue (overlays h2+h1; 8KB) ----
        LDS_FENCE();
        #pragma unroll
        for (int mf = 0; mf < 2; ++mf)
            #pragma unroll
            for (int nf = 0; nf < 4; ++nf)
                #pragma unroll
                for (int r = 0; r < 4; ++r) {
                    const int e3 = mf * 16 + g * 4 + r;
                    const int o  = nf * 16 + li;
                    h3w[e3 * 64 + (o ^ (((e3 >> 2) & 3) << 4))] = RELU(acc3[mf][nf][r]);
                }
        LDS_FENCE();
        __builtin_amdgcn_sched_barrier(0);

        // ---- per-pass sorted-run scan (scalarized run ids) ----
        {
            const int lim = min(32, n - p * 32);
            for (int i = 0; i < lim; ++i) {
                const int d = __builtin_amdgcn_readfirstlane(sd[w * 64 + p * 32 + i].y);
                const float v = h3w[i * 64 + (c ^ (((i >> 2) & 3) << 4))];
                if (d != curd) {
                    if (curd >= 0) {
                        if (curd == prevd || curd == nextd)
                            atomicMax((int*)&aggf[(size_t)curd * 64 + c], __float_as_int(mv));
                        else
                            aggf[(size_t)curd * 64 + c] = mv;
                    }
                    curd = d;
                    mv = v;
                } else {
                    mv = fmaxf(mv, v);
                }
            }
        }
        LDS_FENCE();   // scan reads complete before next pass overlays scratch
    } // p

    if (curd >= 0) {
        if (curd == prevd || curd == nextd)
            atomicMax((int*)&aggf[(size_t)curd * 64 + c], __float_as_int(mv));
        else
            aggf[(size_t)curd * 64 + c] = mv;
    }
}

// ---------- node MLP: out = relu(agg @ wg + bg) ----------
__global__ __launch_bounds__(256, 4)
void node_out_kernel(const float* __restrict__ agg, const float* __restrict__ wg,
                     const float* __restrict__ bg, float* __restrict__ out, int N)
{
    __shared__ float wgs[64 * 64];
    for (int i = threadIdx.x; i < 64 * 64; i += blockDim.x) wgs[i] = wg[i];
    __syncthreads();

    const int t = blockIdx.x * blockDim.x + threadIdx.x;
    const int nidx = t >> 4;
    const int og = t & 15;
    if (nidx >= N) return;

    const float4* aggv = reinterpret_cast<const float4*>(agg + (size_t)nidx * 64);
    const float4* wgsv = reinterpret_cast<const float4*>(wgs);

    float4 acc = reinterpret_cast<const float4*>(bg)[og];
    #pragma unroll
    for (int kg = 0; kg < 16; ++kg) {
        float4 a = aggv[kg];
        float4 w0 = wgsv[(kg * 4 + 0) * 16 + og];
        float4 w1 = wgsv[(kg * 4 + 1) * 16 + og];
        float4 w2 = wgsv[(kg * 4 + 2) * 16 + og];
        float4 w3 = wgsv[(kg * 4 + 3) * 16 + og];
        acc.x += a.x * w0.x + a.y * w1.x + a.z * w2.x + a.w * w3.x;
        acc.y += a.x * w0.y + a.y * w1.y + a.z * w2.y + a.w * w3.y;
        acc.z += a.x * w0.z + a.y * w1.z + a.z * w2.z + a.w * w3.z;
        acc.w += a.x * w0.w + a.y * w1.w + a.z * w2.w + a.w * w3.w;
    }
    float4 r;
    r.x = RELU(acc.x); r.y = RELU(acc.y); r.z = RELU(acc.z); r.w = RELU(acc.w);
    reinterpret_cast<float4*>(out)[(size_t)nidx * 16 + og] = r;
}

extern "C" void kernel_launch(void* const* d_in, const int* in_sizes, int n_in,
                              void* d_out, int out_size, void* d_ws, size_t ws_size,
                              hipStream_t stream)
{
    const float* x   = (const float*)d_in[0];
    const float* pos = (const float*)d_in[1];
    const float* w1  = (const float*)d_in[2];
    const float* b1  = (const float*)d_in[3];
    const float* w2  = (const float*)d_in[4];
    const float* b2  = (const float*)d_in[5];
    const float* w3  = (const float*)d_in[6];
    const float* b3  = (const float*)d_in[7];
    const float* wg  = (const float*)d_in[8];
    const float* bg  = (const float*)d_in[9];
    const int*   ei  = (const int*)d_in[10];

    const int N = in_sizes[0] / 16;
    const int E = in_sizes[10] / 2;

    // ws layout (int elements): [cnt N][agg N*64][cur N][bsum 128][ep 2E][images]
    int* wsi  = (int*)d_ws;
    int* cnt  = wsi;                               // [N]
    int* agg  = wsi + N;                           // [N*64]
    int* cur  = wsi + N + N * 64;                  // [N]
    int* bsum = wsi + N * 66;                      // [128]
    int2* ep  = (int2*)(wsi + N * 66 + 128);       // [E]
    _Float16* w2img = (_Float16*)(wsi + N * 66 + 128 + 2 * E);  // [8192]
    _Float16* w3img = w2img + 8192;                              // [8192]
    _Float16* w1img = w3img + 8192;                              // [2048]

    hipMemsetAsync(cnt, 0, (size_t)N * 65 * sizeof(int), stream);

    const int eb = (E + 255) / 256;
    const int NB = (N + 1023) / 1024;
    prep_weights<<<8, 256, 0, stream>>>(w1, w2, w3, w1img, w2img, w3img);
    count_kernel<<<eb, 256, 0, stream>>>(ei, E, cnt);
    scan1_kernel<<<NB, 1024, 0, stream>>>(cnt, cur, bsum, N);
    scan2_kernel<<<1, 128, 0, stream>>>(bsum, NB);
    scan3_kernel<<<(N + 255) / 256, 256, 0, stream>>>(cur, bsum, N);
    scatter_kernel<<<eb, 256, 0, stream>>>(ei, E, cur, ep);
    edge_mlp_mfma<<<(E + 255) / 256, 256, 0, stream>>>(
        x, pos, w1img, b1, w2img, b2, w3img, b3, ep, E, (float*)agg);
    node_out_kernel<<<(N * 16 + 255) / 256, 256, 0, stream>>>(
        (const float*)agg, wg, bg, (float*)d_out, N);
}

// Round 7
// 341.547 us; speedup vs baseline: 13.2191x; 1.3552x over previous
//
#include <hip/hip_runtime.h>

// PointNetLayer round 7: aux-pipeline diet. count records rank (atomicAdd return)
// so scatter needs no atomics; scan3 folded into scatter (reads bsum directly);
// prep_weights merged into count kernel. Edge kernel identical to round 6.

typedef __attribute__((ext_vector_type(8))) _Float16 half8;
typedef __attribute__((ext_vector_type(4))) float floatx4;

#define RELU(v) fmaxf((v), 0.0f)
#define LDS_FENCE() asm volatile("s_waitcnt lgkmcnt(0)" ::: "memory")

// ---------- pass 1: weight prep (blocks 0..7) + histogram with rank (blocks 8..) ----------
// w2img: [o=0..127][cpr=0..7][j=0..7]  element = w2[k][o], k = (cpr^(o&7))*8 + j
// w3img: [o=0..63][cpr=0..15][j=0..7]  element = w3[k][o], k = ((cpr^(o&7)))*8 + j
// w1img: [o=0..63][c=0..3][j=0..7]     element = w1[k][o], k = (c^(o&3))*8 + j, 0 if k>=19
__global__ void count_prep_kernel(const int* __restrict__ ei, int E,
                                  int* __restrict__ cnt, int* __restrict__ rnk,
                                  const float* __restrict__ w1, const float* __restrict__ w2,
                                  const float* __restrict__ w3,
                                  _Float16* __restrict__ w1img, _Float16* __restrict__ w2img,
                                  _Float16* __restrict__ w3img)
{
    const int b = blockIdx.x;
    if (b < 8) {
        const int t = b * 256 + threadIdx.x;
        const int stride = 8 * 256;
        for (int i = t; i < 128 * 64; i += stride) {
            int o = i >> 6, cpr = (i >> 3) & 7, j = i & 7;
            int k = ((cpr ^ (o & 7)) << 3) | j;
            w2img[i] = (_Float16)w2[k * 128 + o];
        }
        for (int i = t; i < 64 * 128; i += stride) {
            int o = i >> 7, cpr = (i >> 3) & 15, j = i & 7;
            int kc = cpr ^ (o & 7);
            int k = (kc << 3) | j;
            w3img[i] = (_Float16)w3[k * 64 + o];
        }
        for (int i = t; i < 64 * 32; i += stride) {
            int o = i >> 5, c = (i >> 3) & 3, j = i & 7;
            int k = ((c ^ (o & 3)) << 3) | j;
            w1img[i] = (k < 19) ? (_Float16)w1[k * 64 + o] : (_Float16)0.0f;
        }
    } else {
        const int e = (b - 8) * 256 + threadIdx.x;
        if (e < E) rnk[e] = atomicAdd(&cnt[ei[E + e]], 1);
    }
}

// ---------- pass 2: parallel exclusive scan (2 kernels; global add folded into scatter) ----------
__global__ __launch_bounds__(1024)
void scan1_kernel(const int* __restrict__ cnt, int* __restrict__ cur,
                  int* __restrict__ bsum, int N)
{
    __shared__ int sh[1024];
    const int t = threadIdx.x, b = blockIdx.x;
    const int idx = b * 1024 + t;
    int v = (idx < N) ? cnt[idx] : 0;
    sh[t] = v;
    __syncthreads();
    for (int off = 1; off < 1024; off <<= 1) {
        int o = (t >= off) ? sh[t - off] : 0;
        __syncthreads();
        sh[t] += o;
        __syncthreads();
    }
    if (idx < N) cur[idx] = sh[t] - v;   // exclusive within block
    if (t == 1023) bsum[b] = sh[t];
}

__global__ __launch_bounds__(128)
void scan2_kernel(int* __restrict__ bsum, int NB)
{
    __shared__ int sh[128];
    const int t = threadIdx.x;
    int v = (t < NB) ? bsum[t] : 0;
    sh[t] = v;
    __syncthreads();
    for (int off = 1; off < 128; off <<= 1) {
        int o = (t >= off) ? sh[t - off] : 0;
        __syncthreads();
        sh[t] += o;
        __syncthreads();
    }
    if (t < NB) bsum[t] = sh[t] - v;     // exclusive block offsets
}

// ---------- pass 3: atomic-free scatter ----------
__global__ void scatter_kernel(const int* __restrict__ ei, int E,
                               const int* __restrict__ cur, const int* __restrict__ bsum,
                               const int* __restrict__ rnk, int2* __restrict__ ep)
{
    int e = blockIdx.x * blockDim.x + threadIdx.x;
    if (e >= E) return;
    int s = ei[e], d = ei[E + e];
    int p = cur[d] + bsum[d >> 10] + rnk[e];
    ep[p] = make_int2(s, d);
}

__device__ __forceinline__ void load_msg(float* msg, int s, int d,
                                         const float* __restrict__ x,
                                         const float* __restrict__ pos)
{
    const float4* xv = reinterpret_cast<const float4*>(x + (size_t)s * 16);
    float4 x0 = xv[0], x1 = xv[1], x2 = xv[2], x3 = xv[3];
    msg[0] = x0.x;  msg[1] = x0.y;  msg[2] = x0.z;  msg[3] = x0.w;
    msg[4] = x1.x;  msg[5] = x1.y;  msg[6] = x1.z;  msg[7] = x1.w;
    msg[8] = x2.x;  msg[9] = x2.y;  msg[10] = x2.z; msg[11] = x2.w;
    msg[12] = x3.x; msg[13] = x3.y; msg[14] = x3.z; msg[15] = x3.w;
    msg[16] = pos[(size_t)s * 3 + 0] - pos[(size_t)d * 3 + 0];
    msg[17] = pos[(size_t)s * 3 + 1] - pos[(size_t)d * 3 + 1];
    msg[18] = pos[(size_t)s * 3 + 2] - pos[(size_t)d * 3 + 2];
}

// ---------- main fused edge kernel (identical to round 6) ----------
__global__ __launch_bounds__(256, 2)
void edge_mlp_mfma(const float* __restrict__ x, const float* __restrict__ pos,
                   const _Float16* __restrict__ w1img, const float* __restrict__ b1,
                   const _Float16* __restrict__ w2img, const float* __restrict__ b2,
                   const _Float16* __restrict__ w3img, const float* __restrict__ b3,
                   const int2* __restrict__ ep, int E, float* __restrict__ aggf)
{
    __shared__ __align__(16) _Float16 w2s[128 * 64];    // 16 KB
    __shared__ __align__(16) _Float16 w3s[64 * 128];    // 16 KB
    __shared__ __align__(16) _Float16 w1s[64 * 32];     // 4 KB
    __shared__ __align__(16) float b1s[64], b2s[128], b3s[64];
    __shared__ __align__(16) int2 sd[256];              // 2 KB
    __shared__ __align__(16) float scratch[4][2048];    // 8 KB per wave

    const int t  = threadIdx.x;
    const int bs = blockIdx.x * 256;

    {
        const int4* s2 = (const int4*)w2img;
        int4* d2 = (int4*)w2s;
        for (int i = t; i < 1024; i += 256) d2[i] = s2[i];
        const int4* s3 = (const int4*)w3img;
        int4* d3 = (int4*)w3s;
        for (int i = t; i < 1024; i += 256) d3[i] = s3[i];
        const int4* s1 = (const int4*)w1img;
        int4* d1 = (int4*)w1s;
        if (t < 256) d1[t] = s1[t];
    }
    if (t < 64) { b1s[t] = b1[t]; b3s[t] = b3[t]; }
    if (t < 128) b2s[t] = b2[t];
    sd[t] = ep[min(bs + t, E - 1)];
    __syncthreads();

    const int lane = t & 63;
    const int w    = t >> 6;
    const int g    = lane >> 4;
    const int li   = lane & 15;
    const int W    = bs + w * 64;
    float*    h3w  = &scratch[w][0];
    _Float16* msgh = (_Float16*)&scratch[w][0];      // [32e][4c][8j] fp16, 2KB
    _Float16* h2h  = (_Float16*)&scratch[w][0];      // [32e][8c][8j] fp16, 4KB
    _Float16* h1s  = (_Float16*)&scratch[w][1024];   // [32e][8c][8j] fp16, 4KB

    const int n = min(64, E - W);
    const int c = lane;
    int prevd = -2, nextd = -2;
    if (n > 0) {
        prevd = (W == 0) ? -2 : __builtin_amdgcn_readfirstlane((w > 0) ? sd[w * 64 - 1].y : ep[W - 1].y);
        nextd = (W + n >= E) ? -2 : __builtin_amdgcn_readfirstlane((w < 3) ? sd[(w + 1) * 64].y : ep[W + 64].y);
    }
    int curd = -1;
    float mv = 0.0f;

    #pragma unroll
    for (int p = 0; p < 2; ++p) {
        if (lane < 32) {
            const int el = lane;
            int2 e0 = sd[w * 64 + p * 32 + el];
            float m[19];
            load_msg(m, e0.x, e0.y, x, pos);
            _Float16 hv[32];
            #pragma unroll
            for (int k = 0; k < 19; ++k) hv[k] = (_Float16)m[k];
            #pragma unroll
            for (int k = 19; k < 32; ++k) hv[k] = (_Float16)0.0f;
            const int sw = (el >> 1) & 3;
            #pragma unroll
            for (int cch = 0; cch < 4; ++cch) {
                half8 hh;
                #pragma unroll
                for (int j = 0; j < 8; ++j) hh[j] = hv[cch * 8 + j];
                *(half8*)&msgh[el * 32 + (cch ^ sw) * 8] = hh;
            }
        }
        LDS_FENCE();
        __builtin_amdgcn_sched_barrier(0);

        // ---- layer 1 MFMA: [32e x 32k] x [32k x 64o] ----
        {
            half8 w1f[4];
            #pragma unroll
            for (int nf = 0; nf < 4; ++nf) {
                const int o = nf * 16 + li;
                w1f[nf] = *(const half8*)&w1s[o * 32 + (g ^ (o & 3)) * 8];
            }
            floatx4 acc1[2][4];
            #pragma unroll
            for (int nf = 0; nf < 4; ++nf) {
                float bv = b1s[nf * 16 + li];
                acc1[0][nf] = (floatx4){bv, bv, bv, bv};
                acc1[1][nf] = (floatx4){bv, bv, bv, bv};
            }
            #pragma unroll
            for (int mf = 0; mf < 2; ++mf) {
                const int el = mf * 16 + li;
                half8 af = *(const half8*)&msgh[el * 32 + (g ^ ((el >> 1) & 3)) * 8];
                #pragma unroll
                for (int nf = 0; nf < 4; ++nf)
                    acc1[mf][nf] = __builtin_amdgcn_mfma_f32_16x16x32_f16(af, w1f[nf], acc1[mf][nf], 0, 0, 0);
            }
            LDS_FENCE();
            #pragma unroll
            for (int mf = 0; mf < 2; ++mf)
                #pragma unroll
                for (int nf = 0; nf < 4; ++nf)
                    #pragma unroll
                    for (int r = 0; r < 4; ++r) {
                        const int e2 = mf * 16 + g * 4 + r;
                        const int o  = nf * 16 + li;
                        const int cpr = (o >> 3) ^ (e2 & 7);
                        h1s[e2 * 64 + cpr * 8 + (o & 7)] = (_Float16)RELU(acc1[mf][nf][r]);
                    }
        }
        LDS_FENCE();
        __builtin_amdgcn_sched_barrier(0);

        // ---- load L2 A-frags from h1s ----
        half8 afr[2][2];
        #pragma unroll
        for (int ks = 0; ks < 2; ++ks)
            #pragma unroll
            for (int mf = 0; mf < 2; ++mf) {
                const int e2 = mf * 16 + li;
                const int cpr = (ks * 4 + g) ^ (e2 & 7);
                afr[mf][ks] = *(const half8*)&h1s[e2 * 64 + cpr * 8];
            }

        // ---- L2 (double-pumped 64-col halves) + L3 accumulate ----
        floatx4 acc3[2][4];
        #pragma unroll
        for (int nf = 0; nf < 4; ++nf) {
            float bv = b3s[nf * 16 + li];
            acc3[0][nf] = (floatx4){bv, bv, bv, bv};
            acc3[1][nf] = (floatx4){bv, bv, bv, bv};
        }

        #pragma unroll
        for (int hf = 0; hf < 2; ++hf) {
            floatx4 acc2[2][4];
            #pragma unroll
            for (int nf = 0; nf < 4; ++nf) {
                float bv = b2s[hf * 64 + nf * 16 + li];
                acc2[0][nf] = (floatx4){bv, bv, bv, bv};
                acc2[1][nf] = (floatx4){bv, bv, bv, bv};
            }
            #pragma unroll
            for (int ks = 0; ks < 2; ++ks) {
                #pragma unroll
                for (int nf = 0; nf < 4; ++nf) {
                    const int o = hf * 64 + nf * 16 + li;
                    const int cpr = (ks * 4 + g) ^ (o & 7);
                    half8 bfr = *(const half8*)&w2s[o * 64 + cpr * 8];
                    acc2[0][nf] = __builtin_amdgcn_mfma_f32_16x16x32_f16(afr[0][ks], bfr, acc2[0][nf], 0, 0, 0);
                    acc2[1][nf] = __builtin_amdgcn_mfma_f32_16x16x32_f16(afr[1][ks], bfr, acc2[1][nf], 0, 0, 0);
                }
            }
            LDS_FENCE();
            #pragma unroll
            for (int mf = 0; mf < 2; ++mf)
                #pragma unroll
                for (int nf = 0; nf < 4; ++nf)
                    #pragma unroll
                    for (int r = 0; r < 4; ++r) {
                        const int e2 = mf * 16 + g * 4 + r;
                        const int ol = nf * 16 + li;
                        const int cpr = (ol >> 3) ^ (e2 & 7);
                        h2h[e2 * 64 + cpr * 8 + (ol & 7)] = (_Float16)RELU(acc2[mf][nf][r]);
                    }
            LDS_FENCE();
            __builtin_amdgcn_sched_barrier(0);
            #pragma unroll
            for (int ks_l = 0; ks_l < 2; ++ks_l) {
                const int ksg = hf * 2 + ks_l;
                half8 a2[2], b3f[4];
                #pragma unroll
                for (int mf = 0; mf < 2; ++mf) {
                    const int e2 = mf * 16 + li;
                    const int ca = (ks_l * 4 + g) ^ (e2 & 7);
                    a2[mf] = *(const half8*)&h2h[e2 * 64 + ca * 8];
                }
                #pragma unroll
                for (int nf = 0; nf < 4; ++nf) {
                    const int o = nf * 16 + li;
                    const int cb = (ksg * 4 + g) ^ (o & 7);
                    b3f[nf] = *(const half8*)&w3s[o * 128 + cb * 8];
                }
                #pragma unroll
                for (int mf = 0; mf < 2; ++mf)
                    #pragma unroll
                    for (int nf = 0; nf < 4; ++nf)
                        acc3[mf][nf] = __builtin_amdgcn_mfma_f32_16x16x32_f16(a2[mf], b3f[nf], acc3[mf][nf], 0, 0, 0);
            }
        } // hf

        // ---- h3 epilogue ----
        LDS_FENCE();
        #pragma unroll
        for (int mf = 0; mf < 2; ++mf)
            #pragma unroll
            for (int nf = 0; nf < 4; ++nf)
                #pragma unroll
                for (int r = 0; r < 4; ++r) {
                    const int e3 = mf * 16 + g * 4 + r;
                    const int o  = nf * 16 + li;
                    h3w[e3 * 64 + (o ^ (((e3 >> 2) & 3) << 4))] = RELU(acc3[mf][nf][r]);
                }
        LDS_FENCE();
        __builtin_amdgcn_sched_barrier(0);

        // ---- per-pass sorted-run scan ----
        {
            const int lim = min(32, n - p * 32);
            for (int i = 0; i < lim; ++i) {
                const int d = __builtin_amdgcn_readfirstlane(sd[w * 64 + p * 32 + i].y);
                const float v = h3w[i * 64 + (c ^ (((i >> 2) & 3) << 4))];
                if (d != curd) {
                    if (curd >= 0) {
                        if (curd == prevd || curd == nextd)
                            atomicMax((int*)&aggf[(size_t)curd * 64 + c], __float_as_int(mv));
                        else
                            aggf[(size_t)curd * 64 + c] = mv;
                    }
                    curd = d;
                    mv = v;
                } else {
                    mv = fmaxf(mv, v);
                }
            }
        }
        LDS_FENCE();
    } // p

    if (curd >= 0) {
        if (curd == prevd || curd == nextd)
            atomicMax((int*)&aggf[(size_t)curd * 64 + c], __float_as_int(mv));
        else
            aggf[(size_t)curd * 64 + c] = mv;
    }
}

// ---------- node MLP: out = relu(agg @ wg + bg) ----------
__global__ __launch_bounds__(256, 4)
void node_out_kernel(const float* __restrict__ agg, const float* __restrict__ wg,
                     const float* __restrict__ bg, float* __restrict__ out, int N)
{
    __shared__ float wgs[64 * 64];
    for (int i = threadIdx.x; i < 64 * 64; i += blockDim.x) wgs[i] = wg[i];
    __syncthreads();

    const int t = blockIdx.x * blockDim.x + threadIdx.x;
    const int nidx = t >> 4;
    const int og = t & 15;
    if (nidx >= N) return;

    const float4* aggv = reinterpret_cast<const float4*>(agg + (size_t)nidx * 64);
    const float4* wgsv = reinterpret_cast<const float4*>(wgs);

    float4 acc = reinterpret_cast<const float4*>(bg)[og];
    #pragma unroll
    for (int kg = 0; kg < 16; ++kg) {
        float4 a = aggv[kg];
        float4 w0 = wgsv[(kg * 4 + 0) * 16 + og];
        float4 w1 = wgsv[(kg * 4 + 1) * 16 + og];
        float4 w2 = wgsv[(kg * 4 + 2) * 16 + og];
        float4 w3 = wgsv[(kg * 4 + 3) * 16 + og];
        acc.x += a.x * w0.x + a.y * w1.x + a.z * w2.x + a.w * w3.x;
        acc.y += a.x * w0.y + a.y * w1.y + a.z * w2.y + a.w * w3.y;
        acc.z += a.x * w0.z + a.y * w1.z + a.z * w2.z + a.w * w3.z;
        acc.w += a.x * w0.w + a.y * w1.w + a.z * w2.w + a.w * w3.w;
    }
    float4 r;
    r.x = RELU(acc.x); r.y = RELU(acc.y); r.z = RELU(acc.z); r.w = RELU(acc.w);
    reinterpret_cast<float4*>(out)[(size_t)nidx * 16 + og] = r;
}

extern "C" void kernel_launch(void* const* d_in, const int* in_sizes, int n_in,
                              void* d_out, int out_size, void* d_ws, size_t ws_size,
                              hipStream_t stream)
{
    const float* x   = (const float*)d_in[0];
    const float* pos = (const float*)d_in[1];
    const float* w1  = (const float*)d_in[2];
    const float* b1  = (const float*)d_in[3];
    const float* w2  = (const float*)d_in[4];
    const float* b2  = (const float*)d_in[5];
    const float* w3  = (const float*)d_in[6];
    const float* b3  = (const float*)d_in[7];
    const float* wg  = (const float*)d_in[8];
    const float* bg  = (const float*)d_in[9];
    const int*   ei  = (const int*)d_in[10];

    const int N = in_sizes[0] / 16;
    const int E = in_sizes[10] / 2;

    // ws layout (int elements): [cnt N][agg N*64][cur N][bsum 128][ep 2E][rank E][images]
    int* wsi  = (int*)d_ws;
    int* cnt  = wsi;                               // [N]
    int* agg  = wsi + N;                           // [N*64]
    int* cur  = wsi + N + N * 64;                  // [N]
    int* bsum = wsi + N * 66;                      // [128]
    int2* ep  = (int2*)(wsi + N * 66 + 128);       // [E]
    int* rnk  = wsi + N * 66 + 128 + 2 * E;        // [E]
    _Float16* w2img = (_Float16*)(wsi + N * 66 + 128 + 3 * E);  // [8192]
    _Float16* w3img = w2img + 8192;                              // [8192]
    _Float16* w1img = w3img + 8192;                              // [2048]

    hipMemsetAsync(cnt, 0, (size_t)N * 65 * sizeof(int), stream);

    const int eb = (E + 255) / 256;
    const int NB = (N + 1023) / 1024;
    count_prep_kernel<<<eb + 8, 256, 0, stream>>>(ei, E, cnt, rnk,
                                                  w1, w2, w3, w1img, w2img, w3img);
    scan1_kernel<<<NB, 1024, 0, stream>>>(cnt, cur, bsum, N);
    scan2_kernel<<<1, 128, 0, stream>>>(bsum, NB);
    scatter_kernel<<<eb, 256, 0, stream>>>(ei, E, cur, bsum, rnk, ep);
    edge_mlp_mfma<<<(E + 255) / 256, 256, 0, stream>>>(
        x, pos, w1img, b1, w2img, b2, w3img, b3, ep, E, (float*)agg);
    node_out_kernel<<<(N * 16 + 255) / 256, 256, 0, stream>>>(
        (const float*)agg, wg, bg, (float*)d_out, N);
}